// Round 12
// baseline (1306.242 us; speedup 1.0000x reference)
//
#include <hip/hip_runtime.h>
#include <hip/hip_bf16.h>
#include <math.h>

using bf16 = __hip_bfloat16;
using short8  = __attribute__((ext_vector_type(8))) short;   // 8 bf16 (4 VGPRs)
using floatx4 = __attribute__((ext_vector_type(4))) float;   // MFMA accumulator

__device__ __forceinline__ float b2f(bf16 v){ return __bfloat162float(v); }
__device__ __forceinline__ bf16  f2b(float v){ return __float2bfloat16(v); }
// dtype-adaptive load of a "reference float32" tensor that may arrive as bf16 or fp32
__device__ __forceinline__ float loadf(const void* p, size_t i, bool f32){
    return f32 ? ((const float*)p)[i] : b2f(((const bf16*)p)[i]);
}
// async global->LDS DMA, 16 B per lane; lds dest = wave-uniform base + lane*16
__device__ __forceinline__ void gload16(const void* g, void* l){
    __builtin_amdgcn_global_load_lds(
        (const __attribute__((address_space(1))) unsigned int*)g,
        (__attribute__((address_space(3))) unsigned int*)l, 16, 0, 0);
}
__device__ __forceinline__ void bar(){
    asm volatile("" ::: "memory");
    __builtin_amdgcn_s_barrier();
    asm volatile("" ::: "memory");
}
template<int Nn> __device__ __forceinline__ void vmwait(){
    if constexpr (Nn == 0)      asm volatile("s_waitcnt vmcnt(0)" ::: "memory");
    else if constexpr (Nn == 3) asm volatile("s_waitcnt vmcnt(3)" ::: "memory");
    else                        asm volatile("s_waitcnt vmcnt(4)" ::: "memory");
}
// rule #18: after an asm lgkmcnt wait, fence the scheduler so MFMAs can't hoist above it
__device__ __forceinline__ void lgkm0_fence(){
    asm volatile("s_waitcnt lgkmcnt(0)" ::: "memory");
    __builtin_amdgcn_sched_barrier(0);
}

// B=8, H=W=64, C=768, HEADS=12, WS=8, SHIFT=4, N=64, hd=64, L=4096, Mtot=32768
#define FIXED_WS 14303488

// ---------------- runtime dtype detection ----------------
__global__ void detect_k(const void* __restrict__ x, int* __restrict__ flag){
    __shared__ int cnt;
    if (threadIdx.x == 0) cnt = 0;
    __syncthreads();
    const unsigned short* u = (const unsigned short*)x;
    int local = 0;
    #pragma unroll
    for (int i = 0; i < 16; ++i){
        unsigned int w = u[threadIdx.x * 16 + i];
        float v = __uint_as_float(w << 16);
        float a = fabsf(v);
        if (!(a <= 1e4f) || (v != 0.f && a < 1e-20f)) local++;   // NaN fails (a<=1e4)
    }
    atomicAdd(&cnt, local);
    __syncthreads();
    if (threadIdx.x == 0) *flag = (cnt > 200) ? 1 : 0;
}

// ---------------- weight transpose (K x N -> N x K), dual-dtype source ----------------
__global__ void transpose_k(const void* __restrict__ W, bf16* __restrict__ WT, int K, int N,
                            const int* __restrict__ dflag){
    const bool f32 = (*dflag != 0);
    __shared__ bf16 t[32][33];
    int k0 = blockIdx.y * 32, n0 = blockIdx.x * 32;
    int tx = threadIdx.x, ty = threadIdx.y;           // block (32,8)
    #pragma unroll
    for (int r = ty; r < 32; r += 8) t[r][tx] = f2b(loadf(W, (size_t)(k0 + r) * N + n0 + tx, f32));
    __syncthreads();
    #pragma unroll
    for (int r = ty; r < 32; r += 8) WT[(size_t)(n0 + r) * K + k0 + tx] = t[tx][r];
}

// ---------------- adaLN: mod = silu(c) @ w_adaln + b_adaln; 4-way K-split, wave-coalesced j --------
__global__ __launch_bounds__(256) void adaln_k(const void* __restrict__ c, const void* __restrict__ w,
                                               const void* __restrict__ bv, float* __restrict__ mod,
                                               const int* __restrict__ dflag){
    const bool f32 = (*dflag != 0);
    int b = blockIdx.y;
    int jl = threadIdx.x & 63;                        // j within wave: coalesced 64-wide
    int part = threadIdx.x >> 6;                      // K-quarter per wave
    int j = blockIdx.x * 64 + jl;                     // [0,4608)
    __shared__ float sc[768];
    for (int k = threadIdx.x; k < 768; k += 256){
        float v = loadf(c, b * 768 + k, f32);
        sc[k] = v / (1.f + __expf(-v));
    }
    __syncthreads();
    float acc = 0.f;
    int k0 = part * 192;
    #pragma unroll 4
    for (int k = k0; k < k0 + 192; ++k) acc += sc[k] * loadf(w, (size_t)k * 4608 + j, f32);
    __shared__ float red[4][64];
    red[part][jl] = acc;
    __syncthreads();
    if (part == 0)
        mod[b * 4608 + j] = red[0][jl] + red[1][jl] + red[2][jl] + red[3][jl] + loadf(bv, j, f32);
}

// ---------------- block reduction helper (256 threads) ----------------
__device__ __forceinline__ float2 block_reduce_sum2(float s, float s2){
    #pragma unroll
    for (int m = 32; m >= 1; m >>= 1){
        s  += __shfl_xor(s,  m, 64);
        s2 += __shfl_xor(s2, m, 64);
    }
    __shared__ float red[8];
    int wave = threadIdx.x >> 6;
    if ((threadIdx.x & 63) == 0){ red[wave] = s; red[4 + wave] = s2; }
    __syncthreads();
    return make_float2(red[0] + red[1] + red[2] + red[3],
                       red[4] + red[5] + red[6] + red[7]);
}

// ---------------- LN + modulate + roll(-4,-4) + window partition (chunked) ----------------
__global__ __launch_bounds__(256) void ln_mod_win_k(const void* __restrict__ x, const float* __restrict__ mod,
                                                    bf16* __restrict__ win, int roff,
                                                    const int* __restrict__ dflag){
    const bool f32 = (*dflag != 0);
    int r = roff + blockIdx.x;                        // global window-layout token
    int bw = r >> 6, n = r & 63;
    int b = bw >> 6, widx = bw & 63;
    int hh = (((widx >> 3) << 3) + (n >> 3) + 4) & 63;
    int ww = (((widx & 7) << 3) + (n & 7) + 4) & 63;
    size_t xo = ((size_t)b * 4096 + hh * 64 + ww) * 768;
    int t = threadIdx.x;
    float v0 = loadf(x, xo + t, f32), v1 = loadf(x, xo + t + 256, f32), v2 = loadf(x, xo + t + 512, f32);
    float2 ss = block_reduce_sum2(v0 + v1 + v2, v0 * v0 + v1 * v1 + v2 * v2);
    float mu = ss.x * (1.f / 768.f);
    float rstd = rsqrtf(ss.y * (1.f / 768.f) - mu * mu + 1e-6f);
    const float* mb = mod + b * 4608;                 // [sh_msa | sc_msa | ...]
    bf16* wr = win + (size_t)blockIdx.x * 768;        // chunk-local
    wr[t]       = f2b((v0 - mu) * rstd * (1.f + mb[768 + t])       + mb[t]);
    wr[t + 256] = f2b((v1 - mu) * rstd * (1.f + mb[768 + t + 256]) + mb[t + 256]);
    wr[t + 512] = f2b((v2 - mu) * rstd * (1.f + mb[768 + t + 512]) + mb[t + 512]);
}

// ---------------- LN + modulate (MLP branch; x1 lives in d_out, dtype = output mode) ----------------
__global__ __launch_bounds__(256) void ln_mod2_k(const void* __restrict__ x1, const float* __restrict__ mod,
                                                 bf16* __restrict__ h2, int roff,
                                                 const int* __restrict__ dflag){
    const bool f32 = (*dflag != 0);
    int t0 = roff + blockIdx.x;                       // global image token
    int b = t0 >> 12;
    size_t xo = (size_t)t0 * 768;
    int t = threadIdx.x;
    float v0 = loadf(x1, xo + t, f32), v1 = loadf(x1, xo + t + 256, f32), v2 = loadf(x1, xo + t + 512, f32);
    float2 ss = block_reduce_sum2(v0 + v1 + v2, v0 * v0 + v1 * v1 + v2 * v2);
    float mu = ss.x * (1.f / 768.f);
    float rstd = rsqrtf(ss.y * (1.f / 768.f) - mu * mu + 1e-6f);
    const float* mb = mod + b * 4608;                 // sh_mlp @2304, sc_mlp @3072
    bf16* wr = h2 + (size_t)blockIdx.x * 768;         // chunk-local
    wr[t]       = f2b((v0 - mu) * rstd * (1.f + mb[3072 + t])       + mb[2304 + t]);
    wr[t + 256] = f2b((v1 - mu) * rstd * (1.f + mb[3072 + t + 256]) + mb[2304 + t + 256]);
    wr[t + 512] = f2b((v2 - mu) * rstd * (1.f + mb[3072 + t + 512]) + mb[2304 + t + 512]);
}

// ---------------- windowed attention: register-tiled 4x4, one block per (window, head) ----------------
__global__ __launch_bounds__(256) void attn_k(const bf16* __restrict__ qkv, const void* __restrict__ maskm,
                                              const int* __restrict__ rel, const void* __restrict__ rpb,
                                              bf16* __restrict__ ao, int woff,
                                              const int* __restrict__ dflag){
    const bool f32 = (*dflag != 0);
    __shared__ bf16  qs[64][68];
    __shared__ float ks[64][65];
    __shared__ bf16  vs[64][64];
    __shared__ float Ps[64][68];
    int blk = blockIdx.x;
    int head = blk % 12;
    int bw = blk / 12;                                // chunk-local window
    int tid = threadIdx.x;
    const bf16* base = qkv + (size_t)bw * 64 * 2304 + head * 64;
    for (int e4 = tid; e4 < 1024; e4 += 256){
        int n = e4 >> 4, d4 = (e4 & 15) * 4;
        size_t o = (size_t)n * 2304 + d4;
        ushort4 qv = *(const ushort4*)(base + o);
        ushort4 kv = *(const ushort4*)(base + o + 768);
        ushort4 vv = *(const ushort4*)(base + o + 1536);
        bf16 q0, q1, q2, q3;
        *(unsigned short*)&q0 = qv.x; *(unsigned short*)&q1 = qv.y;
        *(unsigned short*)&q2 = qv.z; *(unsigned short*)&q3 = qv.w;
        qs[n][d4]     = f2b(b2f(q0) * 0.125f);        // q * hd^-0.5 (exact in bf16)
        qs[n][d4 + 1] = f2b(b2f(q1) * 0.125f);
        qs[n][d4 + 2] = f2b(b2f(q2) * 0.125f);
        qs[n][d4 + 3] = f2b(b2f(q3) * 0.125f);
        bf16 k0, k1, k2, k3;
        *(unsigned short*)&k0 = kv.x; *(unsigned short*)&k1 = kv.y;
        *(unsigned short*)&k2 = kv.z; *(unsigned short*)&k3 = kv.w;
        ks[n][d4]     = b2f(k0); ks[n][d4 + 1] = b2f(k1);
        ks[n][d4 + 2] = b2f(k2); ks[n][d4 + 3] = b2f(k3);
        *(ushort4*)&vs[n][d4] = vv;
    }
    __syncthreads();
    size_t mo = (size_t)((woff + bw) & 63) * 4096;    // window idx within batch
    int i0 = (tid >> 4) * 4, j0 = (tid & 15) * 4;
    {
        float acc[4][4];
        #pragma unroll
        for (int a = 0; a < 4; ++a)
            #pragma unroll
            for (int b2 = 0; b2 < 4; ++b2) acc[a][b2] = 0.f;
        #pragma unroll 8
        for (int d = 0; d < 64; ++d){
            float qv[4], kv[4];
            #pragma unroll
            for (int a = 0; a < 4; ++a) qv[a] = b2f(qs[i0 + a][d]);
            #pragma unroll
            for (int b2 = 0; b2 < 4; ++b2) kv[b2] = ks[j0 + b2][d];
            #pragma unroll
            for (int a = 0; a < 4; ++a)
                #pragma unroll
                for (int b2 = 0; b2 < 4; ++b2) acc[a][b2] += qv[a] * kv[b2];
        }
        #pragma unroll
        for (int a = 0; a < 4; ++a){
            int i = i0 + a;
            int4 r4 = *(const int4*)&rel[i * 64 + j0];
            float4 o4;
            o4.x = acc[a][0] + loadf(rpb, (size_t)r4.x * 12 + head, f32) + loadf(maskm, mo + i * 64 + j0,     f32);
            o4.y = acc[a][1] + loadf(rpb, (size_t)r4.y * 12 + head, f32) + loadf(maskm, mo + i * 64 + j0 + 1, f32);
            o4.z = acc[a][2] + loadf(rpb, (size_t)r4.z * 12 + head, f32) + loadf(maskm, mo + i * 64 + j0 + 2, f32);
            o4.w = acc[a][3] + loadf(rpb, (size_t)r4.w * 12 + head, f32) + loadf(maskm, mo + i * 64 + j0 + 3, f32);
            *(float4*)&Ps[i][j0] = o4;
        }
    }
    __syncthreads();
    {   // wave-parallel softmax: 4 threads per row (row = tid>>2, 16 cols each)
        int row = tid >> 2, p0 = (tid & 3) * 16;
        float mx = -1e30f;
        #pragma unroll
        for (int j = 0; j < 16; ++j) mx = fmaxf(mx, Ps[row][p0 + j]);
        mx = fmaxf(mx, __shfl_xor(mx, 1, 64));
        mx = fmaxf(mx, __shfl_xor(mx, 2, 64));
        float sum = 0.f;
        float ev[16];
        #pragma unroll
        for (int j = 0; j < 16; ++j){ ev[j] = __expf(Ps[row][p0 + j] - mx); sum += ev[j]; }
        sum += __shfl_xor(sum, 1, 64);
        sum += __shfl_xor(sum, 2, 64);
        float inv = 1.f / sum;
        #pragma unroll
        for (int j = 0; j < 16; ++j) Ps[row][p0 + j] = ev[j] * inv;
    }
    __syncthreads();
    {
        int d0 = j0;
        float po[4][4];
        #pragma unroll
        for (int a = 0; a < 4; ++a)
            #pragma unroll
            for (int b2 = 0; b2 < 4; ++b2) po[a][b2] = 0.f;
        #pragma unroll 8
        for (int j = 0; j < 64; ++j){
            float pv[4];
            #pragma unroll
            for (int a = 0; a < 4; ++a) pv[a] = Ps[i0 + a][j];
            ushort4 v4 = *(const ushort4*)&vs[j][d0];
            bf16 w0, w1, w2, w3;
            *(unsigned short*)&w0 = v4.x; *(unsigned short*)&w1 = v4.y;
            *(unsigned short*)&w2 = v4.z; *(unsigned short*)&w3 = v4.w;
            float vv[4] = {b2f(w0), b2f(w1), b2f(w2), b2f(w3)};
            #pragma unroll
            for (int a = 0; a < 4; ++a)
                #pragma unroll
                for (int b2 = 0; b2 < 4; ++b2) po[a][b2] += pv[a] * vv[b2];
        }
        #pragma unroll
        for (int a = 0; a < 4; ++a){
            ushort4 s4;
            bf16 t0 = f2b(po[a][0]), t1 = f2b(po[a][1]), t2 = f2b(po[a][2]), t3 = f2b(po[a][3]);
            s4.x = *(unsigned short*)&t0; s4.y = *(unsigned short*)&t1;
            s4.z = *(unsigned short*)&t2; s4.w = *(unsigned short*)&t3;
            *(ushort4*)&ao[((size_t)bw * 64 + i0 + a) * 768 + head * 64 + d0] = s4;
        }
    }
}

// ---------------- MFMA bf16 GEMM #1: 256x256 tile, 8 waves, wave-tile 128x64 (big-N GEMMs) --------
// r12: the r11 family is LDS-BW-bound at 768 B/MFMA (per wave-step: 8 KB frag reads + 4 KB staging
// for 16 MFMA; per CU at 3 blk = 144 KB/step vs 240 cy/SIMD MFMA -> util 20%, measured). This
// kernel halves bytes/MFMA: wave tile 128x64 -> 12 frag reads per 32 MFMA (500 B/MFMA).
// 512 threads = 8 waves (2M x 4N), BK=32, THREE 32 KB buffers (96 KB -> 1 blk/CU, 2 waves/SIMD).
// Same r6-proven schedule + persistence (mb-fastest tile ranges, one unbroken pipeline,
// vmcnt->0 only at the block tail). Same staging/swizzle algebra (row bases multiples of 16).
// EPI: 0 = store bf16 (qkv); 1 = exact GELU bf16 (fc1). Narrow-N GEMMs stay on gemm_k<_,64>.
template<int EPI>
__global__ __launch_bounds__(512, 2)
void gemm256_k(const bf16* __restrict__ A, const bf16* __restrict__ BT,
               const void* __restrict__ bias, void* __restrict__ Cout,
               int N, int K, const int* __restrict__ dflag, int nMB, int total){
    const bool f32 = (*dflag != 0);
    __shared__ __align__(16) bf16 As[3][256 * 32];
    __shared__ __align__(16) bf16 Bs[3][256 * 32];

    int tid = threadIdx.x;
    int w = tid >> 6, lane = tid & 63;
    int wm = (w >> 2) * 128, wn = (w & 3) * 64;       // 2M x 4N wave grid
    int lrow = lane & 15, lq = lane >> 4;

    int G = (int)gridDim.x, bid = (int)blockIdx.x;
    int q = total / G, r = total % G;
    int myLen = q + (bid < r ? 1 : 0);
    int first = bid * q + (bid < r ? bid : r);
    const int nkt = K >> 5;                           // 24 (K=768)
    int TS = myLen * nkt;

    // staging: wave w covers rows [w*32, w*32+32) of A and of B (2 gload16 each, LPT=4).
    // lane's LDS slot row = base + (lane>>2), chunk slot = lane&3, carrying data chunk
    // c = ((lane&3)-((lane>>3)&3))&3 (inverse of the (r>>1) rotation; bases mult of 16).
    int sc8 = ((((lane & 3) - ((lane >> 3) & 3)) & 3)) * 8;
    int srw = lane >> 2;
    int lofs0 = (w * 32) * 32;
    int lofs1 = (w * 32 + 16) * 32;

    // fragment read offsets (inverse swizzle; (row>>1)&3 == (lrow>>1)&3)
    int fsw = ((lq + ((lrow >> 1) & 3)) & 3) * 8;
    int aoff = (wm + lrow) * 32 + fsw;
    int boff = (wn + lrow) * 32 + fsw;

    floatx4 acc[8][4];
    #pragma unroll
    for (int i = 0; i < 8; ++i)
        #pragma unroll
        for (int j = 0; j < 4; ++j) acc[i][j] = floatx4{0.f, 0.f, 0.f, 0.f};

    int sIdx = first, sT = 0;
    const bf16 *gA, *gB;
    auto setPtrs = [&](){
        int m0s = (sIdx % nMB) * 256;
        int n0s = (sIdx / nMB) * 256;
        gA = A  + (size_t)(m0s + w * 32 + srw) * K + sc8;
        gB = BT + (size_t)(n0s + w * 32 + srw) * K + sc8;
    };
    setPtrs();
    auto stageStep = [&](int buf){
        size_t kof = (size_t)sT * 32;
        gload16(gA + kof,                  As[buf] + lofs0);
        gload16(gA + kof + (size_t)16 * K, As[buf] + lofs1);
        gload16(gB + kof,                  Bs[buf] + lofs0);
        gload16(gB + kof + (size_t)16 * K, Bs[buf] + lofs1);
        if (++sT == nkt){ sT = 0; ++sIdx; setPtrs(); }
    };

    stageStep(0); stageStep(1);
    vmwait<4>();                                      // step 0 landed; step 1 in flight
    bar();

    int rIdx = first, rT = 0;
    int rm0 = (rIdx % nMB) * 256, rn0 = (rIdx / nMB) * 256;
    float bb[4];
    int bN0 = -1;
    int cur = 0, nx2 = 2;

    for (int T = 0; T < TS; ++T){
        short8 af[8], bfr[4];
        #pragma unroll
        for (int f = 0; f < 8; ++f) af[f]  = *(const short8*)(As[cur] + aoff + f * 512);
        #pragma unroll
        for (int f = 0; f < 4; ++f) bfr[f] = *(const short8*)(Bs[cur] + boff + f * 512);
        bool more = (T + 2 < TS);
        if (more) stageStep(nx2);                     // buf nx2's readers drained 2 bars ago
        lgkm0_fence();                                // frags in regs; MFMAs pinned below
        __builtin_amdgcn_s_setprio(1);
        #pragma unroll
        for (int mf = 0; mf < 8; ++mf)
            #pragma unroll
            for (int nf = 0; nf < 4; ++nf)
                acc[mf][nf] = __builtin_amdgcn_mfma_f32_16x16x32_bf16(af[mf], bfr[nf], acc[mf][nf], 0, 0, 0);
        __builtin_amdgcn_s_setprio(0);
        if (T + 1 < TS){
            if (more) vmwait<4>();                    // T+1 landed; T+2 in flight
            else      vmwait<0>();                    // block tail: drain
            bar();
        }
        cur = (cur == 2) ? 0 : cur + 1;
        nx2 = (nx2 == 2) ? 0 : nx2 + 1;
        if (++rT == nkt){                             // tile complete -> epilogue
            rT = 0;
            if (rn0 != bN0){
                bN0 = rn0;
                #pragma unroll
                for (int nf = 0; nf < 4; ++nf) bb[nf] = loadf(bias, rn0 + wn + nf * 16 + lrow, f32);
            }
            #pragma unroll
            for (int mf = 0; mf < 8; ++mf){
                #pragma unroll
                for (int nf = 0; nf < 4; ++nf){
                    #pragma unroll
                    for (int rr = 0; rr < 4; ++rr){
                        int grow = rm0 + wm + mf * 16 + lq * 4 + rr;
                        int gcol = rn0 + wn + nf * 16 + lrow;
                        float v = acc[mf][nf][rr] + bb[nf];
                        if (EPI == 0){
                            ((bf16*)Cout)[(size_t)grow * N + gcol] = f2b(v);
                        } else {
                            float g = 0.5f * v * (1.f + erff(v * 0.70710678118654752f));
                            ((bf16*)Cout)[(size_t)grow * N + gcol] = f2b(g);
                        }
                    }
                }
            }
            #pragma unroll
            for (int i = 0; i < 8; ++i)
                #pragma unroll
                for (int j = 0; j < 4; ++j) acc[i][j] = floatx4{0.f, 0.f, 0.f, 0.f};
            ++rIdx;
            rm0 = (rIdx % nMB) * 256; rn0 = (rIdx / nMB) * 256;
        }
    }
}

// ---------------- MFMA bf16 GEMM #2: persistent BN=64 engine (narrow-N: proj, fc2) ----------------
// r11-proven: 128x64 tile, 256 threads (4 waves of 32x64), BK=32, THREE 12 KB buffers (36 KB ->
// 4 blk/CU), persistent mb-fastest ranges, counted vmcnt (never 0 mid-loop), hoisted bias.
// EPI: 2 proj epilogue (unwindow+roll+residual+gate -> x1); 3 fc2 epilogue (out = x1 + g_mlp*v).
template<int EPI>
__global__ __launch_bounds__(256, 4)
void gemm_k(const bf16* __restrict__ A, const bf16* __restrict__ BT,
            const void* __restrict__ bias, void* __restrict__ Cout,
            int N, int K, int roff,
            const void* __restrict__ xres, const float* __restrict__ mod,
            const void* __restrict__ x1,
            const int* __restrict__ dflag, int nMB, int total){
    constexpr int LPT = 3;
    const bool f32 = (*dflag != 0);
    __shared__ __align__(16) bf16 As[3][128 * 32];
    __shared__ __align__(16) bf16 Bs[3][64 * 32];

    int tid = threadIdx.x;
    int wave = tid >> 6, lane = tid & 63;
    int wm = wave * 32, wn = 0;
    int lrow = lane & 15, lq = lane >> 4;

    int G = (int)gridDim.x, bid = (int)blockIdx.x;
    int q = total / G, r = total % G;
    int myLen = q + (bid < r ? 1 : 0);
    int first = bid * q + (bid < r ? bid : r);
    const int nkt = K >> 5;
    int TS = myLen * nkt;

    int sc8 = ((((lane & 3) - ((lane >> 3) & 3)) & 3)) * 8;
    int srw = lane >> 2;
    int lofsA0 = (wave * 32) * 32;
    int lofsA1 = (wave * 32 + 16) * 32;
    int lofsB  = (wave * 16) * 32;
    int wB     = wave * 16;

    int fsw = ((lq + ((lrow >> 1) & 3)) & 3) * 8;
    int aoff = (wm + lrow) * 32 + fsw;
    int boff = (wn + lrow) * 32 + fsw;

    floatx4 acc[2][4];
    #pragma unroll
    for (int i = 0; i < 2; ++i)
        #pragma unroll
        for (int j = 0; j < 4; ++j) acc[i][j] = floatx4{0.f, 0.f, 0.f, 0.f};

    int sIdx = first, sT = 0;
    const bf16 *gA, *gB;
    auto setPtrs = [&](){
        int m0s = (sIdx % nMB) * 128;
        int n0s = (sIdx / nMB) * 64;
        gA = A  + (size_t)(m0s + wave * 32 + srw) * K + sc8;
        gB = BT + (size_t)(n0s + wB + srw) * K + sc8;
    };
    setPtrs();
    auto stageStep = [&](int buf){
        size_t kof = (size_t)sT * 32;
        gload16(gA + kof,                  As[buf] + lofsA0);
        gload16(gA + kof + (size_t)16 * K, As[buf] + lofsA1);
        gload16(gB + kof,                  Bs[buf] + lofsB);
        if (++sT == nkt){ sT = 0; ++sIdx; setPtrs(); }
    };

    stageStep(0); stageStep(1);
    vmwait<LPT>();
    bar();

    int rIdx = first, rT = 0;
    int rm0 = (rIdx % nMB) * 128, rn0 = (rIdx / nMB) * 64;
    float bb[4];
    int bN0 = -1;
    int cur = 0, nx2 = 2;

    for (int T = 0; T < TS; ++T){
        short8 af[2], bfr[4];
        #pragma unroll
        for (int f = 0; f < 2; ++f) af[f]  = *(const short8*)(As[cur] + aoff + f * 512);
        #pragma unroll
        for (int f = 0; f < 4; ++f) bfr[f] = *(const short8*)(Bs[cur] + boff + f * 512);
        bool more = (T + 2 < TS);
        if (more) stageStep(nx2);
        lgkm0_fence();
        __builtin_amdgcn_s_setprio(1);
        #pragma unroll
        for (int mf = 0; mf < 2; ++mf)
            #pragma unroll
            for (int nf = 0; nf < 4; ++nf)
                acc[mf][nf] = __builtin_amdgcn_mfma_f32_16x16x32_bf16(af[mf], bfr[nf], acc[mf][nf], 0, 0, 0);
        __builtin_amdgcn_s_setprio(0);
        if (T + 1 < TS){
            if (more) vmwait<LPT>();
            else      vmwait<0>();
            bar();
        }
        cur = (cur == 2) ? 0 : cur + 1;
        nx2 = (nx2 == 2) ? 0 : nx2 + 1;
        if (++rT == nkt){
            rT = 0;
            if (rn0 != bN0){
                bN0 = rn0;
                #pragma unroll
                for (int nf = 0; nf < 4; ++nf) bb[nf] = loadf(bias, rn0 + wn + nf * 16 + lrow, f32);
            }
            #pragma unroll
            for (int mf = 0; mf < 2; ++mf){
                #pragma unroll
                for (int nf = 0; nf < 4; ++nf){
                    #pragma unroll
                    for (int rr = 0; rr < 4; ++rr){
                        int grow = rm0 + wm + mf * 16 + lq * 4 + rr;
                        int gcol = rn0 + wn + nf * 16 + lrow;
                        float v = acc[mf][nf][rr] + bb[nf];
                        if (EPI == 2){
                            int gr = roff + grow;                    // global window-layout row
                            int bw = gr >> 6, n = gr & 63;
                            int b = bw >> 6, widx = bw & 63;
                            int hh = (((widx >> 3) << 3) + (n >> 3) + 4) & 63;
                            int ww = (((widx & 7) << 3) + (n & 7) + 4) & 63;
                            size_t t = ((size_t)b * 4096 + hh * 64 + ww) * 768 + gcol;
                            float gm = mod[b * 4608 + 1536 + gcol];   // g_msa
                            float res = loadf(xres, t, f32) + gm * v;
                            if (f32) ((float*)Cout)[t] = res; else ((bf16*)Cout)[t] = f2b(res);
                        } else {
                            int gr = roff + grow;                    // global image row
                            int b = gr >> 12;
                            float gm = mod[b * 4608 + 3840 + gcol];   // g_mlp
                            size_t t = (size_t)gr * N + gcol;
                            float res = loadf(x1, t, f32) + gm * v;   // read x1 then overwrite
                            if (f32) ((float*)Cout)[t] = res; else ((bf16*)Cout)[t] = f2b(res);
                        }
                    }
                }
            }
            #pragma unroll
            for (int i = 0; i < 2; ++i)
                #pragma unroll
                for (int j = 0; j < 4; ++j) acc[i][j] = floatx4{0.f, 0.f, 0.f, 0.f};
            ++rIdx;
            rm0 = (rIdx % nMB) * 128; rn0 = (rIdx / nMB) * 64;
        }
    }
}

extern "C" void kernel_launch(void* const* d_in, const int* in_sizes, int n_in,
                              void* d_out, int out_size, void* d_ws, size_t ws_size,
                              hipStream_t stream){
    const void* x       = d_in[0];
    const void* c       = d_in[1];
    const void* maskm   = d_in[2];
    const int*  rel     = (const int*)d_in[3];
    const void* w_adaln = d_in[4];
    const void* b_adaln = d_in[5];
    const void* w_qkv   = d_in[6];
    const void* b_qkv   = d_in[7];
    const void* rpb     = d_in[8];
    const void* w_proj  = d_in[9];
    const void* b_proj  = d_in[10];
    const void* w_fc1   = d_in[11];
    const void* b_fc1   = d_in[12];
    const void* w_fc2   = d_in[13];
    const void* b_fc2   = d_in[14];

    // largest chunk that fits, capped at 8192 so all intermediates stay L3-resident (r10 lesson)
    int Mc = 4096;
    for (int cand = 8192; cand >= 256; cand >>= 1){
        if (FIXED_WS + (size_t)cand * 7680u <= ws_size){ Mc = cand; break; }
    }
    const int nc   = 32768 / Mc;
    const int nMB  = Mc / 128;                         // 128-row tiles (narrow engine)
    const int nMB2 = Mc / 256;                         // 256-row tiles (wide engine)

    char* ws = (char*)d_ws;
    int*  dflag  = (int*)(ws);
    float* mod   = (float*)(ws + 256);
    bf16* wqkvT  = (bf16*)(ws + 147712);
    bf16* wprojT = (bf16*)(ws + 3686656);
    bf16* wfc1T  = (bf16*)(ws + 4866304);
    bf16* wfc2T  = (bf16*)(ws + 9584896);
    bf16* win_c  = (bf16*)(ws + FIXED_WS);                          // Mc*768 bf16 (reused as h2_c)
    bf16* big_c  = (bf16*)(ws + FIXED_WS + (size_t)Mc * 1536);      // Mc*3072 bf16 (qkv / fc1o)
    bf16* ao_c   = (bf16*)(ws + FIXED_WS + (size_t)Mc * 6144);      // Mc*768 bf16 (MSA only)
    void* x1     = d_out;                                           // aliased into d_out
    void* out    = d_out;

    detect_k<<<1, 256, 0, stream>>>(x, dflag);

    dim3 tb(32, 8);
    transpose_k<<<dim3(2304/32, 768/32),  tb, 0, stream>>>(w_qkv,  wqkvT,  768, 2304, dflag);
    transpose_k<<<dim3(768/32,  768/32),  tb, 0, stream>>>(w_proj, wprojT, 768, 768, dflag);
    transpose_k<<<dim3(3072/32, 768/32),  tb, 0, stream>>>(w_fc1,  wfc1T,  768, 3072, dflag);
    transpose_k<<<dim3(768/32,  3072/32), tb, 0, stream>>>(w_fc2,  wfc2T,  3072, 768, dflag);
    adaln_k<<<dim3(72, 8), 256, 0, stream>>>(c, w_adaln, b_adaln, mod, dflag);

    const int G256 = 256;                              // 1 blk/CU (96 KB LDS)
    const int G64  = 1024;                             // 4 blk/CU
    // ---- MSA phase, chunked over windows ----
    for (int ch = 0; ch < nc; ++ch){
        int roff = ch * Mc;
        ln_mod_win_k<<<Mc, 256, 0, stream>>>(x, mod, win_c, roff, dflag);
        int tqkv = nMB2 * 9;                           // 2304/256 = 9 col-tiles
        gemm256_k<0><<<(tqkv < G256 ? tqkv : G256), 512, 0, stream>>>(win_c, wqkvT, b_qkv, big_c,
                                                      2304, 768, dflag, nMB2, tqkv);
        attn_k<<<(Mc/64) * 12, 256, 0, stream>>>(big_c, maskm, rel, rpb, ao_c, roff / 64, dflag);
        int tproj = nMB * 12;                          // 768/64 = 12 col-tiles
        gemm_k<2><<<(tproj < G64 ? tproj : G64), 256, 0, stream>>>(ao_c, wprojT, b_proj, x1,
                                                   768, 768, roff, x, mod, nullptr, dflag, nMB, tproj);
    }
    // ---- MLP phase, chunked over tokens ----
    for (int ch = 0; ch < nc; ++ch){
        int roff = ch * Mc;
        ln_mod2_k<<<Mc, 256, 0, stream>>>(x1, mod, win_c, roff, dflag);
        int tfc1 = nMB2 * 12;                          // 3072/256 = 12 col-tiles
        gemm256_k<1><<<(tfc1 < G256 ? tfc1 : G256), 512, 0, stream>>>(win_c, wfc1T, b_fc1, big_c,
                                                      3072, 768, dflag, nMB2, tfc1);
        int tfc2 = nMB * 12;
        gemm_k<3><<<(tfc2 < G64 ? tfc2 : G64), 256, 0, stream>>>(big_c, wfc2T, b_fc2, out,
                                                   768, 3072, roff, nullptr, mod, x1, dflag, nMB, tfc2);
    }
}

// Round 13
// 1215.041 us; speedup vs baseline: 1.0751x; 1.0751x over previous
//
#include <hip/hip_runtime.h>
#include <hip/hip_bf16.h>
#include <math.h>

using bf16 = __hip_bfloat16;
using short8  = __attribute__((ext_vector_type(8))) short;   // 8 bf16 (4 VGPRs)
using floatx4 = __attribute__((ext_vector_type(4))) float;   // MFMA accumulator

__device__ __forceinline__ float b2f(bf16 v){ return __bfloat162float(v); }
__device__ __forceinline__ bf16  f2b(float v){ return __float2bfloat16(v); }
// dtype-adaptive load of a "reference float32" tensor that may arrive as bf16 or fp32
__device__ __forceinline__ float loadf(const void* p, size_t i, bool f32){
    return f32 ? ((const float*)p)[i] : b2f(((const bf16*)p)[i]);
}
// async global->LDS DMA, 16 B per lane; lds dest = wave-uniform base + lane*16
__device__ __forceinline__ void gload16(const void* g, void* l){
    __builtin_amdgcn_global_load_lds(
        (const __attribute__((address_space(1))) unsigned int*)g,
        (__attribute__((address_space(3))) unsigned int*)l, 16, 0, 0);
}
__device__ __forceinline__ void bar(){
    asm volatile("" ::: "memory");
    __builtin_amdgcn_s_barrier();
    asm volatile("" ::: "memory");
}
template<int Nn> __device__ __forceinline__ void vmwait(){
    if constexpr (Nn == 0)      asm volatile("s_waitcnt vmcnt(0)" ::: "memory");
    else if constexpr (Nn == 3) asm volatile("s_waitcnt vmcnt(3)" ::: "memory");
    else                        asm volatile("s_waitcnt vmcnt(4)" ::: "memory");
}
// rule #18: after an asm lgkmcnt wait, fence the scheduler so MFMAs can't hoist above it
__device__ __forceinline__ void lgkm0_fence(){
    asm volatile("s_waitcnt lgkmcnt(0)" ::: "memory");
    __builtin_amdgcn_sched_barrier(0);
}

// B=8, H=W=64, C=768, HEADS=12, WS=8, SHIFT=4, N=64, hd=64, L=4096, Mtot=32768
#define FIXED_WS 14303488

// ---------------- runtime dtype detection ----------------
__global__ void detect_k(const void* __restrict__ x, int* __restrict__ flag){
    __shared__ int cnt;
    if (threadIdx.x == 0) cnt = 0;
    __syncthreads();
    const unsigned short* u = (const unsigned short*)x;
    int local = 0;
    #pragma unroll
    for (int i = 0; i < 16; ++i){
        unsigned int w = u[threadIdx.x * 16 + i];
        float v = __uint_as_float(w << 16);
        float a = fabsf(v);
        if (!(a <= 1e4f) || (v != 0.f && a < 1e-20f)) local++;   // NaN fails (a<=1e4)
    }
    atomicAdd(&cnt, local);
    __syncthreads();
    if (threadIdx.x == 0) *flag = (cnt > 200) ? 1 : 0;
}

// ---------------- weight transpose (K x N -> N x K), dual-dtype source ----------------
__global__ void transpose_k(const void* __restrict__ W, bf16* __restrict__ WT, int K, int N,
                            const int* __restrict__ dflag){
    const bool f32 = (*dflag != 0);
    __shared__ bf16 t[32][33];
    int k0 = blockIdx.y * 32, n0 = blockIdx.x * 32;
    int tx = threadIdx.x, ty = threadIdx.y;           // block (32,8)
    #pragma unroll
    for (int r = ty; r < 32; r += 8) t[r][tx] = f2b(loadf(W, (size_t)(k0 + r) * N + n0 + tx, f32));
    __syncthreads();
    #pragma unroll
    for (int r = ty; r < 32; r += 8) WT[(size_t)(n0 + r) * K + k0 + tx] = t[tx][r];
}

// ---------------- adaLN: mod = silu(c) @ w_adaln + b_adaln; 4-way K-split, wave-coalesced j --------
__global__ __launch_bounds__(256) void adaln_k(const void* __restrict__ c, const void* __restrict__ w,
                                               const void* __restrict__ bv, float* __restrict__ mod,
                                               const int* __restrict__ dflag){
    const bool f32 = (*dflag != 0);
    int b = blockIdx.y;
    int jl = threadIdx.x & 63;                        // j within wave: coalesced 64-wide
    int part = threadIdx.x >> 6;                      // K-quarter per wave
    int j = blockIdx.x * 64 + jl;                     // [0,4608)
    __shared__ float sc[768];
    for (int k = threadIdx.x; k < 768; k += 256){
        float v = loadf(c, b * 768 + k, f32);
        sc[k] = v / (1.f + __expf(-v));
    }
    __syncthreads();
    float acc = 0.f;
    int k0 = part * 192;
    #pragma unroll 4
    for (int k = k0; k < k0 + 192; ++k) acc += sc[k] * loadf(w, (size_t)k * 4608 + j, f32);
    __shared__ float red[4][64];
    red[part][jl] = acc;
    __syncthreads();
    if (part == 0)
        mod[b * 4608 + j] = red[0][jl] + red[1][jl] + red[2][jl] + red[3][jl] + loadf(bv, j, f32);
}

// ---------------- block reduction helper (256 threads) ----------------
__device__ __forceinline__ float2 block_reduce_sum2(float s, float s2){
    #pragma unroll
    for (int m = 32; m >= 1; m >>= 1){
        s  += __shfl_xor(s,  m, 64);
        s2 += __shfl_xor(s2, m, 64);
    }
    __shared__ float red[8];
    int wave = threadIdx.x >> 6;
    if ((threadIdx.x & 63) == 0){ red[wave] = s; red[4 + wave] = s2; }
    __syncthreads();
    return make_float2(red[0] + red[1] + red[2] + red[3],
                       red[4] + red[5] + red[6] + red[7]);
}

// ---------------- LN + modulate + roll(-4,-4) + window partition (chunked) ----------------
__global__ __launch_bounds__(256) void ln_mod_win_k(const void* __restrict__ x, const float* __restrict__ mod,
                                                    bf16* __restrict__ win, int roff,
                                                    const int* __restrict__ dflag){
    const bool f32 = (*dflag != 0);
    int r = roff + blockIdx.x;                        // global window-layout token
    int bw = r >> 6, n = r & 63;
    int b = bw >> 6, widx = bw & 63;
    int hh = (((widx >> 3) << 3) + (n >> 3) + 4) & 63;
    int ww = (((widx & 7) << 3) + (n & 7) + 4) & 63;
    size_t xo = ((size_t)b * 4096 + hh * 64 + ww) * 768;
    int t = threadIdx.x;
    float v0 = loadf(x, xo + t, f32), v1 = loadf(x, xo + t + 256, f32), v2 = loadf(x, xo + t + 512, f32);
    float2 ss = block_reduce_sum2(v0 + v1 + v2, v0 * v0 + v1 * v1 + v2 * v2);
    float mu = ss.x * (1.f / 768.f);
    float rstd = rsqrtf(ss.y * (1.f / 768.f) - mu * mu + 1e-6f);
    const float* mb = mod + b * 4608;                 // [sh_msa | sc_msa | ...]
    bf16* wr = win + (size_t)blockIdx.x * 768;        // chunk-local
    wr[t]       = f2b((v0 - mu) * rstd * (1.f + mb[768 + t])       + mb[t]);
    wr[t + 256] = f2b((v1 - mu) * rstd * (1.f + mb[768 + t + 256]) + mb[t + 256]);
    wr[t + 512] = f2b((v2 - mu) * rstd * (1.f + mb[768 + t + 512]) + mb[t + 512]);
}

// ---------------- LN + modulate (MLP branch; x1 lives in d_out, dtype = output mode) ----------------
__global__ __launch_bounds__(256) void ln_mod2_k(const void* __restrict__ x1, const float* __restrict__ mod,
                                                 bf16* __restrict__ h2, int roff,
                                                 const int* __restrict__ dflag){
    const bool f32 = (*dflag != 0);
    int t0 = roff + blockIdx.x;                       // global image token
    int b = t0 >> 12;
    size_t xo = (size_t)t0 * 768;
    int t = threadIdx.x;
    float v0 = loadf(x1, xo + t, f32), v1 = loadf(x1, xo + t + 256, f32), v2 = loadf(x1, xo + t + 512, f32);
    float2 ss = block_reduce_sum2(v0 + v1 + v2, v0 * v0 + v1 * v1 + v2 * v2);
    float mu = ss.x * (1.f / 768.f);
    float rstd = rsqrtf(ss.y * (1.f / 768.f) - mu * mu + 1e-6f);
    const float* mb = mod + b * 4608;                 // sh_mlp @2304, sc_mlp @3072
    bf16* wr = h2 + (size_t)blockIdx.x * 768;         // chunk-local
    wr[t]       = f2b((v0 - mu) * rstd * (1.f + mb[3072 + t])       + mb[2304 + t]);
    wr[t + 256] = f2b((v1 - mu) * rstd * (1.f + mb[3072 + t + 256]) + mb[2304 + t + 256]);
    wr[t + 512] = f2b((v2 - mu) * rstd * (1.f + mb[3072 + t + 512]) + mb[2304 + t + 512]);
}

// ---------------- windowed attention: register-tiled 4x4, one block per (window, head) ----------------
__global__ __launch_bounds__(256) void attn_k(const bf16* __restrict__ qkv, const void* __restrict__ maskm,
                                              const int* __restrict__ rel, const void* __restrict__ rpb,
                                              bf16* __restrict__ ao, int woff,
                                              const int* __restrict__ dflag){
    const bool f32 = (*dflag != 0);
    __shared__ bf16  qs[64][68];
    __shared__ float ks[64][65];
    __shared__ bf16  vs[64][64];
    __shared__ float Ps[64][68];
    int blk = blockIdx.x;
    int head = blk % 12;
    int bw = blk / 12;                                // chunk-local window
    int tid = threadIdx.x;
    const bf16* base = qkv + (size_t)bw * 64 * 2304 + head * 64;
    for (int e4 = tid; e4 < 1024; e4 += 256){
        int n = e4 >> 4, d4 = (e4 & 15) * 4;
        size_t o = (size_t)n * 2304 + d4;
        ushort4 qv = *(const ushort4*)(base + o);
        ushort4 kv = *(const ushort4*)(base + o + 768);
        ushort4 vv = *(const ushort4*)(base + o + 1536);
        bf16 q0, q1, q2, q3;
        *(unsigned short*)&q0 = qv.x; *(unsigned short*)&q1 = qv.y;
        *(unsigned short*)&q2 = qv.z; *(unsigned short*)&q3 = qv.w;
        qs[n][d4]     = f2b(b2f(q0) * 0.125f);        // q * hd^-0.5 (exact in bf16)
        qs[n][d4 + 1] = f2b(b2f(q1) * 0.125f);
        qs[n][d4 + 2] = f2b(b2f(q2) * 0.125f);
        qs[n][d4 + 3] = f2b(b2f(q3) * 0.125f);
        bf16 k0, k1, k2, k3;
        *(unsigned short*)&k0 = kv.x; *(unsigned short*)&k1 = kv.y;
        *(unsigned short*)&k2 = kv.z; *(unsigned short*)&k3 = kv.w;
        ks[n][d4]     = b2f(k0); ks[n][d4 + 1] = b2f(k1);
        ks[n][d4 + 2] = b2f(k2); ks[n][d4 + 3] = b2f(k3);
        *(ushort4*)&vs[n][d4] = vv;
    }
    __syncthreads();
    size_t mo = (size_t)((woff + bw) & 63) * 4096;    // window idx within batch
    int i0 = (tid >> 4) * 4, j0 = (tid & 15) * 4;
    {
        float acc[4][4];
        #pragma unroll
        for (int a = 0; a < 4; ++a)
            #pragma unroll
            for (int b2 = 0; b2 < 4; ++b2) acc[a][b2] = 0.f;
        #pragma unroll 8
        for (int d = 0; d < 64; ++d){
            float qv[4], kv[4];
            #pragma unroll
            for (int a = 0; a < 4; ++a) qv[a] = b2f(qs[i0 + a][d]);
            #pragma unroll
            for (int b2 = 0; b2 < 4; ++b2) kv[b2] = ks[j0 + b2][d];
            #pragma unroll
            for (int a = 0; a < 4; ++a)
                #pragma unroll
                for (int b2 = 0; b2 < 4; ++b2) acc[a][b2] += qv[a] * kv[b2];
        }
        #pragma unroll
        for (int a = 0; a < 4; ++a){
            int i = i0 + a;
            int4 r4 = *(const int4*)&rel[i * 64 + j0];
            float4 o4;
            o4.x = acc[a][0] + loadf(rpb, (size_t)r4.x * 12 + head, f32) + loadf(maskm, mo + i * 64 + j0,     f32);
            o4.y = acc[a][1] + loadf(rpb, (size_t)r4.y * 12 + head, f32) + loadf(maskm, mo + i * 64 + j0 + 1, f32);
            o4.z = acc[a][2] + loadf(rpb, (size_t)r4.z * 12 + head, f32) + loadf(maskm, mo + i * 64 + j0 + 2, f32);
            o4.w = acc[a][3] + loadf(rpb, (size_t)r4.w * 12 + head, f32) + loadf(maskm, mo + i * 64 + j0 + 3, f32);
            *(float4*)&Ps[i][j0] = o4;
        }
    }
    __syncthreads();
    {   // wave-parallel softmax: 4 threads per row (row = tid>>2, 16 cols each)
        int row = tid >> 2, p0 = (tid & 3) * 16;
        float mx = -1e30f;
        #pragma unroll
        for (int j = 0; j < 16; ++j) mx = fmaxf(mx, Ps[row][p0 + j]);
        mx = fmaxf(mx, __shfl_xor(mx, 1, 64));
        mx = fmaxf(mx, __shfl_xor(mx, 2, 64));
        float sum = 0.f;
        float ev[16];
        #pragma unroll
        for (int j = 0; j < 16; ++j){ ev[j] = __expf(Ps[row][p0 + j] - mx); sum += ev[j]; }
        sum += __shfl_xor(sum, 1, 64);
        sum += __shfl_xor(sum, 2, 64);
        float inv = 1.f / sum;
        #pragma unroll
        for (int j = 0; j < 16; ++j) Ps[row][p0 + j] = ev[j] * inv;
    }
    __syncthreads();
    {
        int d0 = j0;
        float po[4][4];
        #pragma unroll
        for (int a = 0; a < 4; ++a)
            #pragma unroll
            for (int b2 = 0; b2 < 4; ++b2) po[a][b2] = 0.f;
        #pragma unroll 8
        for (int j = 0; j < 64; ++j){
            float pv[4];
            #pragma unroll
            for (int a = 0; a < 4; ++a) pv[a] = Ps[i0 + a][j];
            ushort4 v4 = *(const ushort4*)&vs[j][d0];
            bf16 w0, w1, w2, w3;
            *(unsigned short*)&w0 = v4.x; *(unsigned short*)&w1 = v4.y;
            *(unsigned short*)&w2 = v4.z; *(unsigned short*)&w3 = v4.w;
            float vv[4] = {b2f(w0), b2f(w1), b2f(w2), b2f(w3)};
            #pragma unroll
            for (int a = 0; a < 4; ++a)
                #pragma unroll
                for (int b2 = 0; b2 < 4; ++b2) po[a][b2] += pv[a] * vv[b2];
        }
        #pragma unroll
        for (int a = 0; a < 4; ++a){
            ushort4 s4;
            bf16 t0 = f2b(po[a][0]), t1 = f2b(po[a][1]), t2 = f2b(po[a][2]), t3 = f2b(po[a][3]);
            s4.x = *(unsigned short*)&t0; s4.y = *(unsigned short*)&t1;
            s4.z = *(unsigned short*)&t2; s4.w = *(unsigned short*)&t3;
            *(ushort4*)&ao[((size_t)bw * 64 + i0 + a) * 768 + head * 64 + d0] = s4;
        }
    }
}

// ---------------- MFMA bf16 GEMM: PERSISTENT grid-stride + continuous 3-buffer pipeline ----------------
// r13 = r11 engine verbatim (measured best: 1242 us). Blocks own contiguous mb-fastest tile
// ranges and run one unbroken counted-vmcnt pipeline across tile boundaries; vmcnt hits 0 once
// per block. BN=128 (qkv/fc1): 2x2 waves of 64x64, 48 KB LDS, 3 blk/CU, LPT=4.
// BN=64 (proj/fc2): 4 waves of 32x64, 36 KB LDS, 4 blk/CU, LPT=3.
// Schedule per step (r6-proven): reads(buf T%3) | stage(T+2 -> buf (T+2)%3) | lgkm0+sched_barrier
// | setprio(1) MFMA setprio(0) | vmcnt(LPT) | s_barrier.  WAR ledger: a buffer's readers
// lgkm-drain before their step's exit barrier; the buffer is restaged >= 2 barriers later.
// LDS layout: [rows][32] (64 B/row); chunk c of row r at slot (c+(r>>1))&3 -> ds_read_b128
// 2-way bank-aliased (free; 0 conflicts measured r0-r12).
// EPI: 0 store bf16; 1 exact GELU bf16; 2 proj epilogue (unwindow+roll+residual+gate -> x1);
//      3 fc2 epilogue (out = x1 + g_mlp * v).
template<int EPI, int BN>
__global__ __launch_bounds__(256, (BN == 128) ? 3 : 4)
void gemm_k(const bf16* __restrict__ A, const bf16* __restrict__ BT,
            const void* __restrict__ bias, void* __restrict__ Cout,
            int N, int K, int roff,
            const void* __restrict__ xres, const float* __restrict__ mod,
            const void* __restrict__ x1,
            const int* __restrict__ dflag, int nMB, int total){
    constexpr int MFR = (BN == 128) ? 4 : 2;          // A-frags per wave
    constexpr int LPT = (BN == 128) ? 4 : 3;          // gloads per wave per step
    const bool f32 = (*dflag != 0);
    __shared__ __align__(16) bf16 As[3][128 * 32];
    __shared__ __align__(16) bf16 Bs[3][BN * 32];

    int tid = threadIdx.x;
    int wave = tid >> 6, lane = tid & 63;
    int wm = (BN == 128) ? (wave >> 1) * 64 : wave * 32;
    int wn = (BN == 128) ? (wave & 1) * 64 : 0;
    int lrow = lane & 15, lq = lane >> 4;

    // persistent work range: tiles [first, first+myLen), linear idx = nb*nMB + mb (mb fastest)
    int G = (int)gridDim.x, bid = (int)blockIdx.x;
    int q = total / G, r = total % G;
    int myLen = q + (bid < r ? 1 : 0);
    int first = bid * q + (bid < r ? bid : r);
    const int nkt = K >> 5;                           // 24 or 96
    int TS = myLen * nkt;

    // staging lane geometry (chunk c = ((lane&3)-((lane>>3)&3))&3; base rows mult of 16)
    int sc8 = ((((lane & 3) - ((lane >> 3) & 3)) & 3)) * 8;
    int srw = lane >> 2;
    int lofsA0 = (wave * 32) * 32;
    int lofsA1 = (wave * 32 + 16) * 32;
    int lofsB  = (BN == 128) ? lofsA0 : (wave * 16) * 32;
    int wB     = (BN == 128) ? wave * 32 : wave * 16;

    // fragment read offsets (inverse swizzle; (row>>1)&3 == (lrow>>1)&3)
    int fsw = ((lq + ((lrow >> 1) & 3)) & 3) * 8;
    int aoff = (wm + lrow) * 32 + fsw;
    int boff = (wn + lrow) * 32 + fsw;

    floatx4 acc[MFR][4];
    #pragma unroll
    for (int i = 0; i < MFR; ++i)
        #pragma unroll
        for (int j = 0; j < 4; ++j) acc[i][j] = floatx4{0.f, 0.f, 0.f, 0.f};

    // stage-side state
    int sIdx = first, sT = 0;
    const bf16 *gA, *gB;
    auto setPtrs = [&](){
        int m0s = (sIdx % nMB) * 128;
        int n0s = (sIdx / nMB) * BN;
        gA = A  + (size_t)(m0s + wave * 32 + srw) * K + sc8;
        gB = BT + (size_t)(n0s + wB + srw) * K + sc8;
    };
    setPtrs();
    auto stageStep = [&](int buf){
        size_t kof = (size_t)sT * 32;
        gload16(gA + kof,                  As[buf] + lofsA0);
        gload16(gA + kof + (size_t)16 * K, As[buf] + lofsA1);
        gload16(gB + kof,                  Bs[buf] + lofsB);
        if constexpr (BN == 128)
            gload16(gB + kof + (size_t)16 * K, Bs[buf] + lofsA1);
        if (++sT == nkt){ sT = 0; ++sIdx; setPtrs(); }
    };

    stageStep(0); stageStep(1);
    vmwait<LPT>();                                    // step 0 landed; step 1 in flight
    bar();

    // reader-side state
    int rIdx = first, rT = 0;
    int rm0 = (rIdx % nMB) * 128, rn0 = (rIdx / nMB) * BN;
    float bb[4];
    int bN0 = -1;
    int cur = 0, nx2 = 2;

    for (int T = 0; T < TS; ++T){
        short8 af[MFR], bfr[4];
        #pragma unroll
        for (int f = 0; f < MFR; ++f) af[f]  = *(const short8*)(As[cur] + aoff + f * 512);
        #pragma unroll
        for (int f = 0; f < 4;   ++f) bfr[f] = *(const short8*)(Bs[cur] + boff + f * 512);
        bool more = (T + 2 < TS);
        if (more) stageStep(nx2);                     // buf nx2's readers drained 2 bars ago
        lgkm0_fence();                                // frags in regs; MFMAs pinned below
        __builtin_amdgcn_s_setprio(1);
        #pragma unroll
        for (int mf = 0; mf < MFR; ++mf)
            #pragma unroll
            for (int nf = 0; nf < 4; ++nf)
                acc[mf][nf] = __builtin_amdgcn_mfma_f32_16x16x32_bf16(af[mf], bfr[nf], acc[mf][nf], 0, 0, 0);
        __builtin_amdgcn_s_setprio(0);
        if (T + 1 < TS){
            if (more) vmwait<LPT>();                  // T+1 landed; T+2 in flight
            else      vmwait<0>();                    // block tail: drain
            bar();
        }
        cur = (cur == 2) ? 0 : cur + 1;
        nx2 = (nx2 == 2) ? 0 : nx2 + 1;
        if (++rT == nkt){                             // tile rIdx complete -> epilogue
            rT = 0;
            if (rn0 != bN0){                          // hoist bias for this nb (rare reload)
                bN0 = rn0;
                #pragma unroll
                for (int nf = 0; nf < 4; ++nf) bb[nf] = loadf(bias, rn0 + wn + nf * 16 + lrow, f32);
            }
            #pragma unroll
            for (int mf = 0; mf < MFR; ++mf){
                #pragma unroll
                for (int nf = 0; nf < 4; ++nf){
                    #pragma unroll
                    for (int rr = 0; rr < 4; ++rr){
                        int grow = rm0 + wm + mf * 16 + lq * 4 + rr;   // chunk-local row
                        int gcol = rn0 + wn + nf * 16 + lrow;
                        float v = acc[mf][nf][rr] + bb[nf];
                        if (EPI == 0){
                            ((bf16*)Cout)[(size_t)grow * N + gcol] = f2b(v);
                        } else if (EPI == 1){
                            float g = 0.5f * v * (1.f + erff(v * 0.70710678118654752f));
                            ((bf16*)Cout)[(size_t)grow * N + gcol] = f2b(g);
                        } else if (EPI == 2){
                            int gr = roff + grow;                    // global window-layout row
                            int bw = gr >> 6, n = gr & 63;
                            int b = bw >> 6, widx = bw & 63;
                            int hh = (((widx >> 3) << 3) + (n >> 3) + 4) & 63;
                            int ww = (((widx & 7) << 3) + (n & 7) + 4) & 63;
                            size_t t = ((size_t)b * 4096 + hh * 64 + ww) * 768 + gcol;
                            float gm = mod[b * 4608 + 1536 + gcol];   // g_msa
                            float res = loadf(xres, t, f32) + gm * v;
                            if (f32) ((float*)Cout)[t] = res; else ((bf16*)Cout)[t] = f2b(res);
                        } else {
                            int gr = roff + grow;                    // global image row
                            int b = gr >> 12;
                            float gm = mod[b * 4608 + 3840 + gcol];   // g_mlp
                            size_t t = (size_t)gr * N + gcol;
                            float res = loadf(x1, t, f32) + gm * v;   // read x1 then overwrite
                            if (f32) ((float*)Cout)[t] = res; else ((bf16*)Cout)[t] = f2b(res);
                        }
                    }
                }
            }
            #pragma unroll
            for (int i = 0; i < MFR; ++i)
                #pragma unroll
                for (int j = 0; j < 4; ++j) acc[i][j] = floatx4{0.f, 0.f, 0.f, 0.f};
            ++rIdx;
            rm0 = (rIdx % nMB) * 128; rn0 = (rIdx / nMB) * BN;
        }
    }
}

extern "C" void kernel_launch(void* const* d_in, const int* in_sizes, int n_in,
                              void* d_out, int out_size, void* d_ws, size_t ws_size,
                              hipStream_t stream){
    const void* x       = d_in[0];
    const void* c       = d_in[1];
    const void* maskm   = d_in[2];
    const int*  rel     = (const int*)d_in[3];
    const void* w_adaln = d_in[4];
    const void* b_adaln = d_in[5];
    const void* w_qkv   = d_in[6];
    const void* b_qkv   = d_in[7];
    const void* rpb     = d_in[8];
    const void* w_proj  = d_in[9];
    const void* b_proj  = d_in[10];
    const void* w_fc1   = d_in[11];
    const void* b_fc1   = d_in[12];
    const void* w_fc2   = d_in[13];
    const void* b_fc2   = d_in[14];

    // MSA chunk: capped at 8192 (win 12.5 + qkv 37.7 + ao 12.5 MB all L3-resident; r10 lesson)
    int Mc = 4096;
    for (int cand = 8192; cand >= 256; cand >>= 1){
        if (FIXED_WS + (size_t)cand * 7680u <= ws_size){ Mc = cand; break; }
    }
    // MLP chunk: 16384 if it fits. Reuse-distance check (r10 lesson, applied): fc2 re-reads its
    // 100 MB A-panel once per nb-sweep; distance = 100 MB + ~8-16 MB epilogue stream < 256 MB L3.
    int Mc2 = Mc;
    if (FIXED_WS + 16384ull * 7680u <= ws_size && Mc == 8192) Mc2 = 16384;
    const int nc   = 32768 / Mc;
    const int nc2  = 32768 / Mc2;
    const int nMB  = Mc  / 128;
    const int nMB2 = Mc2 / 128;

    char* ws = (char*)d_ws;
    int*  dflag  = (int*)(ws);
    float* mod   = (float*)(ws + 256);
    bf16* wqkvT  = (bf16*)(ws + 147712);
    bf16* wprojT = (bf16*)(ws + 3686656);
    bf16* wfc1T  = (bf16*)(ws + 4866304);
    bf16* wfc2T  = (bf16*)(ws + 9584896);
    bf16* win_c  = (bf16*)(ws + FIXED_WS);                          // Mc*768 bf16 (reused as h2_c)
    bf16* big_c  = (bf16*)(ws + FIXED_WS + (size_t)Mc * 1536);      // qkv (MSA layout)
    bf16* ao_c   = (bf16*)(ws + FIXED_WS + (size_t)Mc * 6144);      // Mc*768 bf16 (MSA only)
    bf16* h2_c   = (bf16*)(ws + FIXED_WS);                          // Mc2*768 bf16 (MLP layout)
    bf16* fc1o_c = (bf16*)(ws + FIXED_WS + (size_t)Mc2 * 1536);     // Mc2*3072 bf16
    void* x1     = d_out;                                           // aliased into d_out
    void* out    = d_out;

    detect_k<<<1, 256, 0, stream>>>(x, dflag);

    dim3 tb(32, 8);
    transpose_k<<<dim3(2304/32, 768/32),  tb, 0, stream>>>(w_qkv,  wqkvT,  768, 2304, dflag);
    transpose_k<<<dim3(768/32,  768/32),  tb, 0, stream>>>(w_proj, wprojT, 768, 768, dflag);
    transpose_k<<<dim3(3072/32, 768/32),  tb, 0, stream>>>(w_fc1,  wfc1T,  768, 3072, dflag);
    transpose_k<<<dim3(768/32,  3072/32), tb, 0, stream>>>(w_fc2,  wfc2T,  3072, 768, dflag);
    adaln_k<<<dim3(72, 8), 256, 0, stream>>>(c, w_adaln, b_adaln, mod, dflag);

    const int G128 = 768;                              // 3 blk/CU x 256 CU
    const int G64  = 1024;                             // 4 blk/CU x 256 CU
    // ---- MSA phase, chunked over windows ----
    for (int ch = 0; ch < nc; ++ch){
        int roff = ch * Mc;
        ln_mod_win_k<<<Mc, 256, 0, stream>>>(x, mod, win_c, roff, dflag);
        int tqkv = nMB * 18;
        gemm_k<0,128><<<(tqkv < G128 ? tqkv : G128), 256, 0, stream>>>(win_c, wqkvT, b_qkv, big_c,
                                                    2304, 768, 0, nullptr, nullptr, nullptr, dflag, nMB, tqkv);
        attn_k<<<(Mc/64) * 12, 256, 0, stream>>>(big_c, maskm, rel, rpb, ao_c, roff / 64, dflag);
        int tproj = nMB * 12;
        gemm_k<2,64><<<(tproj < G64 ? tproj : G64), 256, 0, stream>>>(ao_c, wprojT, b_proj, x1,
                                                   768, 768, roff, x, mod, nullptr, dflag, nMB, tproj);
    }
    // ---- MLP phase, chunked over tokens (larger chunk: reuse distance stays < L3) ----
    for (int ch = 0; ch < nc2; ++ch){
        int roff = ch * Mc2;
        ln_mod2_k<<<Mc2, 256, 0, stream>>>(x1, mod, h2_c, roff, dflag);
        int tfc1 = nMB2 * 24;
        gemm_k<1,128><<<(tfc1 < G128 ? tfc1 : G128), 256, 0, stream>>>(h2_c, wfc1T, b_fc1, fc1o_c,
                                                    3072, 768, 0, nullptr, nullptr, nullptr, dflag, nMB2, tfc1);
        int tfc2 = nMB2 * 12;
        gemm_k<3,64><<<(tfc2 < G64 ? tfc2 : G64), 256, 0, stream>>>(fc1o_c, wfc2T, b_fc2, out,
                                                   768, 3072, roff, nullptr, mod, x1, dflag, nMB2, tfc2);
    }
}

// Round 14
// 1204.432 us; speedup vs baseline: 1.0845x; 1.0088x over previous
//
#include <hip/hip_runtime.h>
#include <hip/hip_bf16.h>
#include <math.h>

using bf16 = __hip_bfloat16;
using short8  = __attribute__((ext_vector_type(8))) short;   // 8 bf16 (4 VGPRs)
using floatx4 = __attribute__((ext_vector_type(4))) float;   // MFMA accumulator

__device__ __forceinline__ float b2f(bf16 v){ return __bfloat162float(v); }
__device__ __forceinline__ bf16  f2b(float v){ return __float2bfloat16(v); }
// dtype-adaptive load of a "reference float32" tensor that may arrive as bf16 or fp32
__device__ __forceinline__ float loadf(const void* p, size_t i, bool f32){
    return f32 ? ((const float*)p)[i] : b2f(((const bf16*)p)[i]);
}
// async global->LDS DMA, 16 B per lane; lds dest = wave-uniform base + lane*16
__device__ __forceinline__ void gload16(const void* g, void* l){
    __builtin_amdgcn_global_load_lds(
        (const __attribute__((address_space(1))) unsigned int*)g,
        (__attribute__((address_space(3))) unsigned int*)l, 16, 0, 0);
}
__device__ __forceinline__ void bar(){
    asm volatile("" ::: "memory");
    __builtin_amdgcn_s_barrier();
    asm volatile("" ::: "memory");
}
template<int Nn> __device__ __forceinline__ void vmwait(){
    if constexpr (Nn == 0)      asm volatile("s_waitcnt vmcnt(0)" ::: "memory");
    else if constexpr (Nn == 3) asm volatile("s_waitcnt vmcnt(3)" ::: "memory");
    else                        asm volatile("s_waitcnt vmcnt(4)" ::: "memory");
}
// rule #18: after an asm lgkmcnt wait, fence the scheduler so MFMAs can't hoist above it
__device__ __forceinline__ void lgkm0_fence(){
    asm volatile("s_waitcnt lgkmcnt(0)" ::: "memory");
    __builtin_amdgcn_sched_barrier(0);
}

// B=8, H=W=64, C=768, HEADS=12, WS=8, SHIFT=4, N=64, hd=64, L=4096, Mtot=32768
#define FIXED_WS 14303488

// ---------------- runtime dtype detection ----------------
__global__ void detect_k(const void* __restrict__ x, int* __restrict__ flag){
    __shared__ int cnt;
    if (threadIdx.x == 0) cnt = 0;
    __syncthreads();
    const unsigned short* u = (const unsigned short*)x;
    int local = 0;
    #pragma unroll
    for (int i = 0; i < 16; ++i){
        unsigned int w = u[threadIdx.x * 16 + i];
        float v = __uint_as_float(w << 16);
        float a = fabsf(v);
        if (!(a <= 1e4f) || (v != 0.f && a < 1e-20f)) local++;   // NaN fails (a<=1e4)
    }
    atomicAdd(&cnt, local);
    __syncthreads();
    if (threadIdx.x == 0) *flag = (cnt > 200) ? 1 : 0;
}

// ---------------- weight transpose (K x N -> N x K), dual-dtype source ----------------
__global__ void transpose_k(const void* __restrict__ W, bf16* __restrict__ WT, int K, int N,
                            const int* __restrict__ dflag){
    const bool f32 = (*dflag != 0);
    __shared__ bf16 t[32][33];
    int k0 = blockIdx.y * 32, n0 = blockIdx.x * 32;
    int tx = threadIdx.x, ty = threadIdx.y;           // block (32,8)
    #pragma unroll
    for (int r = ty; r < 32; r += 8) t[r][tx] = f2b(loadf(W, (size_t)(k0 + r) * N + n0 + tx, f32));
    __syncthreads();
    #pragma unroll
    for (int r = ty; r < 32; r += 8) WT[(size_t)(n0 + r) * K + k0 + tx] = t[tx][r];
}

// ---------------- adaLN: mod = silu(c) @ w_adaln + b_adaln; 4-way K-split, wave-coalesced j --------
__global__ __launch_bounds__(256) void adaln_k(const void* __restrict__ c, const void* __restrict__ w,
                                               const void* __restrict__ bv, float* __restrict__ mod,
                                               const int* __restrict__ dflag){
    const bool f32 = (*dflag != 0);
    int b = blockIdx.y;
    int jl = threadIdx.x & 63;                        // j within wave: coalesced 64-wide
    int part = threadIdx.x >> 6;                      // K-quarter per wave
    int j = blockIdx.x * 64 + jl;                     // [0,4608)
    __shared__ float sc[768];
    for (int k = threadIdx.x; k < 768; k += 256){
        float v = loadf(c, b * 768 + k, f32);
        sc[k] = v / (1.f + __expf(-v));
    }
    __syncthreads();
    float acc = 0.f;
    int k0 = part * 192;
    #pragma unroll 4
    for (int k = k0; k < k0 + 192; ++k) acc += sc[k] * loadf(w, (size_t)k * 4608 + j, f32);
    __shared__ float red[4][64];
    red[part][jl] = acc;
    __syncthreads();
    if (part == 0)
        mod[b * 4608 + j] = red[0][jl] + red[1][jl] + red[2][jl] + red[3][jl] + loadf(bv, j, f32);
}

// ---------------- block reduction helper (256 threads) ----------------
__device__ __forceinline__ float2 block_reduce_sum2(float s, float s2){
    #pragma unroll
    for (int m = 32; m >= 1; m >>= 1){
        s  += __shfl_xor(s,  m, 64);
        s2 += __shfl_xor(s2, m, 64);
    }
    __shared__ float red[8];
    int wave = threadIdx.x >> 6;
    if ((threadIdx.x & 63) == 0){ red[wave] = s; red[4 + wave] = s2; }
    __syncthreads();
    return make_float2(red[0] + red[1] + red[2] + red[3],
                       red[4] + red[5] + red[6] + red[7]);
}

// ---------------- LN + modulate + roll(-4,-4) + window partition (chunked) ----------------
__global__ __launch_bounds__(256) void ln_mod_win_k(const void* __restrict__ x, const float* __restrict__ mod,
                                                    bf16* __restrict__ win, int roff,
                                                    const int* __restrict__ dflag){
    const bool f32 = (*dflag != 0);
    int r = roff + blockIdx.x;                        // global window-layout token
    int bw = r >> 6, n = r & 63;
    int b = bw >> 6, widx = bw & 63;
    int hh = (((widx >> 3) << 3) + (n >> 3) + 4) & 63;
    int ww = (((widx & 7) << 3) + (n & 7) + 4) & 63;
    size_t xo = ((size_t)b * 4096 + hh * 64 + ww) * 768;
    int t = threadIdx.x;
    float v0 = loadf(x, xo + t, f32), v1 = loadf(x, xo + t + 256, f32), v2 = loadf(x, xo + t + 512, f32);
    float2 ss = block_reduce_sum2(v0 + v1 + v2, v0 * v0 + v1 * v1 + v2 * v2);
    float mu = ss.x * (1.f / 768.f);
    float rstd = rsqrtf(ss.y * (1.f / 768.f) - mu * mu + 1e-6f);
    const float* mb = mod + b * 4608;                 // [sh_msa | sc_msa | ...]
    bf16* wr = win + (size_t)blockIdx.x * 768;        // chunk-local
    wr[t]       = f2b((v0 - mu) * rstd * (1.f + mb[768 + t])       + mb[t]);
    wr[t + 256] = f2b((v1 - mu) * rstd * (1.f + mb[768 + t + 256]) + mb[t + 256]);
    wr[t + 512] = f2b((v2 - mu) * rstd * (1.f + mb[768 + t + 512]) + mb[t + 512]);
}

// ---------------- LN + modulate (MLP branch; x1 lives in d_out, dtype = output mode) ----------------
__global__ __launch_bounds__(256) void ln_mod2_k(const void* __restrict__ x1, const float* __restrict__ mod,
                                                 bf16* __restrict__ h2, int roff,
                                                 const int* __restrict__ dflag){
    const bool f32 = (*dflag != 0);
    int t0 = roff + blockIdx.x;                       // global image token
    int b = t0 >> 12;
    size_t xo = (size_t)t0 * 768;
    int t = threadIdx.x;
    float v0 = loadf(x1, xo + t, f32), v1 = loadf(x1, xo + t + 256, f32), v2 = loadf(x1, xo + t + 512, f32);
    float2 ss = block_reduce_sum2(v0 + v1 + v2, v0 * v0 + v1 * v1 + v2 * v2);
    float mu = ss.x * (1.f / 768.f);
    float rstd = rsqrtf(ss.y * (1.f / 768.f) - mu * mu + 1e-6f);
    const float* mb = mod + b * 4608;                 // sh_mlp @2304, sc_mlp @3072
    bf16* wr = h2 + (size_t)blockIdx.x * 768;         // chunk-local
    wr[t]       = f2b((v0 - mu) * rstd * (1.f + mb[3072 + t])       + mb[2304 + t]);
    wr[t + 256] = f2b((v1 - mu) * rstd * (1.f + mb[3072 + t + 256]) + mb[2304 + t + 256]);
    wr[t + 512] = f2b((v2 - mu) * rstd * (1.f + mb[3072 + t + 512]) + mb[2304 + t + 512]);
}

// ---------------- windowed attention: register-tiled 4x4, one block per (window, head) ----------------
__global__ __launch_bounds__(256) void attn_k(const bf16* __restrict__ qkv, const void* __restrict__ maskm,
                                              const int* __restrict__ rel, const void* __restrict__ rpb,
                                              bf16* __restrict__ ao, int woff,
                                              const int* __restrict__ dflag){
    const bool f32 = (*dflag != 0);
    __shared__ bf16  qs[64][68];
    __shared__ float ks[64][65];
    __shared__ bf16  vs[64][64];
    __shared__ float Ps[64][68];
    int blk = blockIdx.x;
    int head = blk % 12;
    int bw = blk / 12;                                // chunk-local window
    int tid = threadIdx.x;
    const bf16* base = qkv + (size_t)bw * 64 * 2304 + head * 64;
    for (int e4 = tid; e4 < 1024; e4 += 256){
        int n = e4 >> 4, d4 = (e4 & 15) * 4;
        size_t o = (size_t)n * 2304 + d4;
        ushort4 qv = *(const ushort4*)(base + o);
        ushort4 kv = *(const ushort4*)(base + o + 768);
        ushort4 vv = *(const ushort4*)(base + o + 1536);
        bf16 q0, q1, q2, q3;
        *(unsigned short*)&q0 = qv.x; *(unsigned short*)&q1 = qv.y;
        *(unsigned short*)&q2 = qv.z; *(unsigned short*)&q3 = qv.w;
        qs[n][d4]     = f2b(b2f(q0) * 0.125f);        // q * hd^-0.5 (exact in bf16)
        qs[n][d4 + 1] = f2b(b2f(q1) * 0.125f);
        qs[n][d4 + 2] = f2b(b2f(q2) * 0.125f);
        qs[n][d4 + 3] = f2b(b2f(q3) * 0.125f);
        bf16 k0, k1, k2, k3;
        *(unsigned short*)&k0 = kv.x; *(unsigned short*)&k1 = kv.y;
        *(unsigned short*)&k2 = kv.z; *(unsigned short*)&k3 = kv.w;
        ks[n][d4]     = b2f(k0); ks[n][d4 + 1] = b2f(k1);
        ks[n][d4 + 2] = b2f(k2); ks[n][d4 + 3] = b2f(k3);
        *(ushort4*)&vs[n][d4] = vv;
    }
    __syncthreads();
    size_t mo = (size_t)((woff + bw) & 63) * 4096;    // window idx within batch
    int i0 = (tid >> 4) * 4, j0 = (tid & 15) * 4;
    {
        float acc[4][4];
        #pragma unroll
        for (int a = 0; a < 4; ++a)
            #pragma unroll
            for (int b2 = 0; b2 < 4; ++b2) acc[a][b2] = 0.f;
        #pragma unroll 8
        for (int d = 0; d < 64; ++d){
            float qv[4], kv[4];
            #pragma unroll
            for (int a = 0; a < 4; ++a) qv[a] = b2f(qs[i0 + a][d]);
            #pragma unroll
            for (int b2 = 0; b2 < 4; ++b2) kv[b2] = ks[j0 + b2][d];
            #pragma unroll
            for (int a = 0; a < 4; ++a)
                #pragma unroll
                for (int b2 = 0; b2 < 4; ++b2) acc[a][b2] += qv[a] * kv[b2];
        }
        #pragma unroll
        for (int a = 0; a < 4; ++a){
            int i = i0 + a;
            int4 r4 = *(const int4*)&rel[i * 64 + j0];
            float4 o4;
            o4.x = acc[a][0] + loadf(rpb, (size_t)r4.x * 12 + head, f32) + loadf(maskm, mo + i * 64 + j0,     f32);
            o4.y = acc[a][1] + loadf(rpb, (size_t)r4.y * 12 + head, f32) + loadf(maskm, mo + i * 64 + j0 + 1, f32);
            o4.z = acc[a][2] + loadf(rpb, (size_t)r4.z * 12 + head, f32) + loadf(maskm, mo + i * 64 + j0 + 2, f32);
            o4.w = acc[a][3] + loadf(rpb, (size_t)r4.w * 12 + head, f32) + loadf(maskm, mo + i * 64 + j0 + 3, f32);
            *(float4*)&Ps[i][j0] = o4;
        }
    }
    __syncthreads();
    {   // wave-parallel softmax: 4 threads per row (row = tid>>2, 16 cols each)
        int row = tid >> 2, p0 = (tid & 3) * 16;
        float mx = -1e30f;
        #pragma unroll
        for (int j = 0; j < 16; ++j) mx = fmaxf(mx, Ps[row][p0 + j]);
        mx = fmaxf(mx, __shfl_xor(mx, 1, 64));
        mx = fmaxf(mx, __shfl_xor(mx, 2, 64));
        float sum = 0.f;
        float ev[16];
        #pragma unroll
        for (int j = 0; j < 16; ++j){ ev[j] = __expf(Ps[row][p0 + j] - mx); sum += ev[j]; }
        sum += __shfl_xor(sum, 1, 64);
        sum += __shfl_xor(sum, 2, 64);
        float inv = 1.f / sum;
        #pragma unroll
        for (int j = 0; j < 16; ++j) Ps[row][p0 + j] = ev[j] * inv;
    }
    __syncthreads();
    {
        int d0 = j0;
        float po[4][4];
        #pragma unroll
        for (int a = 0; a < 4; ++a)
            #pragma unroll
            for (int b2 = 0; b2 < 4; ++b2) po[a][b2] = 0.f;
        #pragma unroll 8
        for (int j = 0; j < 64; ++j){
            float pv[4];
            #pragma unroll
            for (int a = 0; a < 4; ++a) pv[a] = Ps[i0 + a][j];
            ushort4 v4 = *(const ushort4*)&vs[j][d0];
            bf16 w0, w1, w2, w3;
            *(unsigned short*)&w0 = v4.x; *(unsigned short*)&w1 = v4.y;
            *(unsigned short*)&w2 = v4.z; *(unsigned short*)&w3 = v4.w;
            float vv[4] = {b2f(w0), b2f(w1), b2f(w2), b2f(w3)};
            #pragma unroll
            for (int a = 0; a < 4; ++a)
                #pragma unroll
                for (int b2 = 0; b2 < 4; ++b2) po[a][b2] += pv[a] * vv[b2];
        }
        #pragma unroll
        for (int a = 0; a < 4; ++a){
            ushort4 s4;
            bf16 t0 = f2b(po[a][0]), t1 = f2b(po[a][1]), t2 = f2b(po[a][2]), t3 = f2b(po[a][3]);
            s4.x = *(unsigned short*)&t0; s4.y = *(unsigned short*)&t1;
            s4.z = *(unsigned short*)&t2; s4.w = *(unsigned short*)&t3;
            *(ushort4*)&ao[((size_t)bw * 64 + i0 + a) * 768 + head * 64 + d0] = s4;
        }
    }
}

// ---------------- MFMA bf16 GEMM: PERSISTENT grid-stride + continuous 3-buffer pipeline ----------------
// r14 = r11/r13 engine verbatim. Blocks own contiguous mb-fastest tile ranges and run one
// unbroken counted-vmcnt pipeline across tile boundaries; vmcnt hits 0 once per block.
// BN=128 (qkv/fc1): 2x2 waves of 64x64, 48 KB LDS, 3 blk/CU, LPT=4.
// BN=64 (proj/fc2): 4 waves of 32x64, 36 KB LDS, 4 blk/CU, LPT=3.
// Schedule per step (r6-proven): reads(buf T%3) | stage(T+2 -> buf (T+2)%3) | lgkm0+sched_barrier
// | setprio(1) MFMA setprio(0) | vmcnt(LPT) | s_barrier.  WAR ledger: a buffer's readers
// lgkm-drain before their step's exit barrier; the buffer is restaged >= 2 barriers later.
// LDS layout: [rows][32] (64 B/row); chunk c of row r at slot (c+(r>>1))&3 -> ds_read_b128
// 2-way bank-aliased (free; 0 conflicts measured r0-r13).
// EPI: 0 store bf16; 1 exact GELU bf16; 2 proj epilogue (unwindow+roll+residual+gate -> x1);
//      3 fc2 epilogue (out = x1 + g_mlp * v).
template<int EPI, int BN>
__global__ __launch_bounds__(256, (BN == 128) ? 3 : 4)
void gemm_k(const bf16* __restrict__ A, const bf16* __restrict__ BT,
            const void* __restrict__ bias, void* __restrict__ Cout,
            int N, int K, int roff,
            const void* __restrict__ xres, const float* __restrict__ mod,
            const void* __restrict__ x1,
            const int* __restrict__ dflag, int nMB, int total){
    constexpr int MFR = (BN == 128) ? 4 : 2;          // A-frags per wave
    constexpr int LPT = (BN == 128) ? 4 : 3;          // gloads per wave per step
    const bool f32 = (*dflag != 0);
    __shared__ __align__(16) bf16 As[3][128 * 32];
    __shared__ __align__(16) bf16 Bs[3][BN * 32];

    int tid = threadIdx.x;
    int wave = tid >> 6, lane = tid & 63;
    int wm = (BN == 128) ? (wave >> 1) * 64 : wave * 32;
    int wn = (BN == 128) ? (wave & 1) * 64 : 0;
    int lrow = lane & 15, lq = lane >> 4;

    // persistent work range: tiles [first, first+myLen), linear idx = nb*nMB + mb (mb fastest)
    int G = (int)gridDim.x, bid = (int)blockIdx.x;
    int q = total / G, r = total % G;
    int myLen = q + (bid < r ? 1 : 0);
    int first = bid * q + (bid < r ? bid : r);
    const int nkt = K >> 5;                           // 24 or 96
    int TS = myLen * nkt;

    // staging lane geometry (chunk c = ((lane&3)-((lane>>3)&3))&3; base rows mult of 16)
    int sc8 = ((((lane & 3) - ((lane >> 3) & 3)) & 3)) * 8;
    int srw = lane >> 2;
    int lofsA0 = (wave * 32) * 32;
    int lofsA1 = (wave * 32 + 16) * 32;
    int lofsB  = (BN == 128) ? lofsA0 : (wave * 16) * 32;
    int wB     = (BN == 128) ? wave * 32 : wave * 16;

    // fragment read offsets (inverse swizzle; (row>>1)&3 == (lrow>>1)&3)
    int fsw = ((lq + ((lrow >> 1) & 3)) & 3) * 8;
    int aoff = (wm + lrow) * 32 + fsw;
    int boff = (wn + lrow) * 32 + fsw;

    floatx4 acc[MFR][4];
    #pragma unroll
    for (int i = 0; i < MFR; ++i)
        #pragma unroll
        for (int j = 0; j < 4; ++j) acc[i][j] = floatx4{0.f, 0.f, 0.f, 0.f};

    // stage-side state
    int sIdx = first, sT = 0;
    const bf16 *gA, *gB;
    auto setPtrs = [&](){
        int m0s = (sIdx % nMB) * 128;
        int n0s = (sIdx / nMB) * BN;
        gA = A  + (size_t)(m0s + wave * 32 + srw) * K + sc8;
        gB = BT + (size_t)(n0s + wB + srw) * K + sc8;
    };
    setPtrs();
    auto stageStep = [&](int buf){
        size_t kof = (size_t)sT * 32;
        gload16(gA + kof,                  As[buf] + lofsA0);
        gload16(gA + kof + (size_t)16 * K, As[buf] + lofsA1);
        gload16(gB + kof,                  Bs[buf] + lofsB);
        if constexpr (BN == 128)
            gload16(gB + kof + (size_t)16 * K, Bs[buf] + lofsA1);
        if (++sT == nkt){ sT = 0; ++sIdx; setPtrs(); }
    };

    stageStep(0); stageStep(1);
    vmwait<LPT>();                                    // step 0 landed; step 1 in flight
    bar();

    // reader-side state
    int rIdx = first, rT = 0;
    int rm0 = (rIdx % nMB) * 128, rn0 = (rIdx / nMB) * BN;
    float bb[4];
    int bN0 = -1;
    int cur = 0, nx2 = 2;

    for (int T = 0; T < TS; ++T){
        short8 af[MFR], bfr[4];
        #pragma unroll
        for (int f = 0; f < MFR; ++f) af[f]  = *(const short8*)(As[cur] + aoff + f * 512);
        #pragma unroll
        for (int f = 0; f < 4;   ++f) bfr[f] = *(const short8*)(Bs[cur] + boff + f * 512);
        bool more = (T + 2 < TS);
        if (more) stageStep(nx2);                     // buf nx2's readers drained 2 bars ago
        lgkm0_fence();                                // frags in regs; MFMAs pinned below
        __builtin_amdgcn_s_setprio(1);
        #pragma unroll
        for (int mf = 0; mf < MFR; ++mf)
            #pragma unroll
            for (int nf = 0; nf < 4; ++nf)
                acc[mf][nf] = __builtin_amdgcn_mfma_f32_16x16x32_bf16(af[mf], bfr[nf], acc[mf][nf], 0, 0, 0);
        __builtin_amdgcn_s_setprio(0);
        if (T + 1 < TS){
            if (more) vmwait<LPT>();                  // T+1 landed; T+2 in flight
            else      vmwait<0>();                    // block tail: drain
            bar();
        }
        cur = (cur == 2) ? 0 : cur + 1;
        nx2 = (nx2 == 2) ? 0 : nx2 + 1;
        if (++rT == nkt){                             // tile rIdx complete -> epilogue
            rT = 0;
            if (rn0 != bN0){                          // hoist bias for this nb (rare reload)
                bN0 = rn0;
                #pragma unroll
                for (int nf = 0; nf < 4; ++nf) bb[nf] = loadf(bias, rn0 + wn + nf * 16 + lrow, f32);
            }
            #pragma unroll
            for (int mf = 0; mf < MFR; ++mf){
                #pragma unroll
                for (int nf = 0; nf < 4; ++nf){
                    #pragma unroll
                    for (int rr = 0; rr < 4; ++rr){
                        int grow = rm0 + wm + mf * 16 + lq * 4 + rr;   // chunk-local row
                        int gcol = rn0 + wn + nf * 16 + lrow;
                        float v = acc[mf][nf][rr] + bb[nf];
                        if (EPI == 0){
                            ((bf16*)Cout)[(size_t)grow * N + gcol] = f2b(v);
                        } else if (EPI == 1){
                            float g = 0.5f * v * (1.f + erff(v * 0.70710678118654752f));
                            ((bf16*)Cout)[(size_t)grow * N + gcol] = f2b(g);
                        } else if (EPI == 2){
                            int gr = roff + grow;                    // global window-layout row
                            int bw = gr >> 6, n = gr & 63;
                            int b = bw >> 6, widx = bw & 63;
                            int hh = (((widx >> 3) << 3) + (n >> 3) + 4) & 63;
                            int ww = (((widx & 7) << 3) + (n & 7) + 4) & 63;
                            size_t t = ((size_t)b * 4096 + hh * 64 + ww) * 768 + gcol;
                            float gm = mod[b * 4608 + 1536 + gcol];   // g_msa
                            float res = loadf(xres, t, f32) + gm * v;
                            if (f32) ((float*)Cout)[t] = res; else ((bf16*)Cout)[t] = f2b(res);
                        } else {
                            int gr = roff + grow;                    // global image row
                            int b = gr >> 12;
                            float gm = mod[b * 4608 + 3840 + gcol];   // g_mlp
                            size_t t = (size_t)gr * N + gcol;
                            float res = loadf(x1, t, f32) + gm * v;   // read x1 then overwrite
                            if (f32) ((float*)Cout)[t] = res; else ((bf16*)Cout)[t] = f2b(res);
                        }
                    }
                }
            }
            #pragma unroll
            for (int i = 0; i < MFR; ++i)
                #pragma unroll
                for (int j = 0; j < 4; ++j) acc[i][j] = floatx4{0.f, 0.f, 0.f, 0.f};
            ++rIdx;
            rm0 = (rIdx % nMB) * 128; rn0 = (rIdx / nMB) * BN;
        }
    }
}

extern "C" void kernel_launch(void* const* d_in, const int* in_sizes, int n_in,
                              void* d_out, int out_size, void* d_ws, size_t ws_size,
                              hipStream_t stream){
    const void* x       = d_in[0];
    const void* c       = d_in[1];
    const void* maskm   = d_in[2];
    const int*  rel     = (const int*)d_in[3];
    const void* w_adaln = d_in[4];
    const void* b_adaln = d_in[5];
    const void* w_qkv   = d_in[6];
    const void* b_qkv   = d_in[7];
    const void* rpb     = d_in[8];
    const void* w_proj  = d_in[9];
    const void* b_proj  = d_in[10];
    const void* w_fc1   = d_in[11];
    const void* b_fc1   = d_in[12];
    const void* w_fc2   = d_in[13];
    const void* b_fc2   = d_in[14];

    // MSA chunk: capped at 8192 (win 12.5 + qkv 37.7 + ao 12.5 MB all L3-resident; r10 lesson)
    int Mc = 4096;
    for (int cand = 8192; cand >= 256; cand >>= 1){
        if (FIXED_WS + (size_t)cand * 7680u <= ws_size){ Mc = cand; break; }
    }
    // MLP chunk: 16384 if it fits (fc1 gets 96-step persistent pipelines; proven r13 win).
    // fc2 runs in 8192-row SUB-chunks inside it (r13 lesson: fc2's A-half must be L3-hot).
    int Mc2 = Mc;
    if (FIXED_WS + 16384ull * 7680u <= ws_size && Mc == 8192) Mc2 = 16384;
    const int nc   = 32768 / Mc;
    const int nc2  = 32768 / Mc2;
    const int nMB  = Mc  / 128;
    const int nMB2 = Mc2 / 128;
    const int McF  = (Mc2 > 8192) ? 8192 : Mc2;        // fc2 sub-chunk rows
    const int nMBF = McF / 128;

    char* ws = (char*)d_ws;
    int*  dflag  = (int*)(ws);
    float* mod   = (float*)(ws + 256);
    bf16* wqkvT  = (bf16*)(ws + 147712);
    bf16* wprojT = (bf16*)(ws + 3686656);
    bf16* wfc1T  = (bf16*)(ws + 4866304);
    bf16* wfc2T  = (bf16*)(ws + 9584896);
    bf16* win_c  = (bf16*)(ws + FIXED_WS);                          // Mc*768 bf16
    bf16* big_c  = (bf16*)(ws + FIXED_WS + (size_t)Mc * 1536);      // qkv (MSA layout)
    bf16* ao_c   = (bf16*)(ws + FIXED_WS + (size_t)Mc * 6144);      // Mc*768 bf16 (MSA only)
    bf16* h2_c   = (bf16*)(ws + FIXED_WS);                          // Mc2*768 bf16 (MLP layout)
    bf16* fc1o_c = (bf16*)(ws + FIXED_WS + (size_t)Mc2 * 1536);     // Mc2*3072 bf16
    void* x1     = d_out;                                           // aliased into d_out
    void* out    = d_out;

    detect_k<<<1, 256, 0, stream>>>(x, dflag);

    dim3 tb(32, 8);
    transpose_k<<<dim3(2304/32, 768/32),  tb, 0, stream>>>(w_qkv,  wqkvT,  768, 2304, dflag);
    transpose_k<<<dim3(768/32,  768/32),  tb, 0, stream>>>(w_proj, wprojT, 768, 768, dflag);
    transpose_k<<<dim3(3072/32, 768/32),  tb, 0, stream>>>(w_fc1,  wfc1T,  768, 3072, dflag);
    transpose_k<<<dim3(768/32,  3072/32), tb, 0, stream>>>(w_fc2,  wfc2T,  3072, 768, dflag);
    adaln_k<<<dim3(72, 8), 256, 0, stream>>>(c, w_adaln, b_adaln, mod, dflag);

    const int G128 = 768;                              // 3 blk/CU x 256 CU
    const int G64  = 1024;                             // 4 blk/CU x 256 CU
    // ---- MSA phase, chunked over windows ----
    for (int ch = 0; ch < nc; ++ch){
        int roff = ch * Mc;
        ln_mod_win_k<<<Mc, 256, 0, stream>>>(x, mod, win_c, roff, dflag);
        int tqkv = nMB * 18;
        gemm_k<0,128><<<(tqkv < G128 ? tqkv : G128), 256, 0, stream>>>(win_c, wqkvT, b_qkv, big_c,
                                                    2304, 768, 0, nullptr, nullptr, nullptr, dflag, nMB, tqkv);
        attn_k<<<(Mc/64) * 12, 256, 0, stream>>>(big_c, maskm, rel, rpb, ao_c, roff / 64, dflag);
        int tproj = nMB * 12;
        gemm_k<2,64><<<(tproj < G64 ? tproj : G64), 256, 0, stream>>>(ao_c, wprojT, b_proj, x1,
                                                   768, 768, roff, x, mod, nullptr, dflag, nMB, tproj);
    }
    // ---- MLP phase: big chunk for ln+fc1 (long pipelines), fc2 in L3-hot sub-chunks ----
    for (int ch = 0; ch < nc2; ++ch){
        int roff = ch * Mc2;
        ln_mod2_k<<<Mc2, 256, 0, stream>>>(x1, mod, h2_c, roff, dflag);
        int tfc1 = nMB2 * 24;
        gemm_k<1,128><<<(tfc1 < G128 ? tfc1 : G128), 256, 0, stream>>>(h2_c, wfc1T, b_fc1, fc1o_c,
                                                    3072, 768, 0, nullptr, nullptr, nullptr, dflag, nMB2, tfc1);
        for (int sub = 0; sub < Mc2 / McF; ++sub){
            int tfc2 = nMBF * 12;
            gemm_k<3,64><<<(tfc2 < G64 ? tfc2 : G64), 256, 0, stream>>>(
                fc1o_c + (size_t)sub * McF * 3072, wfc2T, b_fc2, out,
                768, 3072, roff + sub * McF, nullptr, mod, x1, dflag, nMBF, tfc2);
        }
    }
}

// Round 15
// 1153.650 us; speedup vs baseline: 1.1323x; 1.0440x over previous
//
#include <hip/hip_runtime.h>
#include <hip/hip_bf16.h>
#include <math.h>

using bf16 = __hip_bfloat16;
using short8  = __attribute__((ext_vector_type(8))) short;   // 8 bf16 (4 VGPRs)
using floatx4 = __attribute__((ext_vector_type(4))) float;   // MFMA accumulator

__device__ __forceinline__ float b2f(bf16 v){ return __bfloat162float(v); }
__device__ __forceinline__ bf16  f2b(float v){ return __float2bfloat16(v); }
// dtype-adaptive load of a "reference float32" tensor that may arrive as bf16 or fp32
__device__ __forceinline__ float loadf(const void* p, size_t i, bool f32){
    return f32 ? ((const float*)p)[i] : b2f(((const bf16*)p)[i]);
}
// async global->LDS DMA, 16 B per lane; lds dest = wave-uniform base + lane*16
__device__ __forceinline__ void gload16(const void* g, void* l){
    __builtin_amdgcn_global_load_lds(
        (const __attribute__((address_space(1))) unsigned int*)g,
        (__attribute__((address_space(3))) unsigned int*)l, 16, 0, 0);
}
__device__ __forceinline__ void bar(){
    asm volatile("" ::: "memory");
    __builtin_amdgcn_s_barrier();
    asm volatile("" ::: "memory");
}
template<int Nn> __device__ __forceinline__ void vmwait(){
    if constexpr (Nn == 0)      asm volatile("s_waitcnt vmcnt(0)" ::: "memory");
    else if constexpr (Nn == 3) asm volatile("s_waitcnt vmcnt(3)" ::: "memory");
    else                        asm volatile("s_waitcnt vmcnt(4)" ::: "memory");
}
// rule #18: after an asm lgkmcnt wait, fence the scheduler so MFMAs can't hoist above it
__device__ __forceinline__ void lgkm0_fence(){
    asm volatile("s_waitcnt lgkmcnt(0)" ::: "memory");
    __builtin_amdgcn_sched_barrier(0);
}

// B=8, H=W=64, C=768, HEADS=12, WS=8, SHIFT=4, N=64, hd=64, L=4096, Mtot=32768
#define FIXED_WS 14303488

// ---------------- runtime dtype detection ----------------
__global__ void detect_k(const void* __restrict__ x, int* __restrict__ flag){
    __shared__ int cnt;
    if (threadIdx.x == 0) cnt = 0;
    __syncthreads();
    const unsigned short* u = (const unsigned short*)x;
    int local = 0;
    #pragma unroll
    for (int i = 0; i < 16; ++i){
        unsigned int w = u[threadIdx.x * 16 + i];
        float v = __uint_as_float(w << 16);
        float a = fabsf(v);
        if (!(a <= 1e4f) || (v != 0.f && a < 1e-20f)) local++;   // NaN fails (a<=1e4)
    }
    atomicAdd(&cnt, local);
    __syncthreads();
    if (threadIdx.x == 0) *flag = (cnt > 200) ? 1 : 0;
}

// ---------------- weight transpose (K x N -> N x K), dual-dtype source ----------------
__global__ void transpose_k(const void* __restrict__ W, bf16* __restrict__ WT, int K, int N,
                            const int* __restrict__ dflag){
    const bool f32 = (*dflag != 0);
    __shared__ bf16 t[32][33];
    int k0 = blockIdx.y * 32, n0 = blockIdx.x * 32;
    int tx = threadIdx.x, ty = threadIdx.y;           // block (32,8)
    #pragma unroll
    for (int r = ty; r < 32; r += 8) t[r][tx] = f2b(loadf(W, (size_t)(k0 + r) * N + n0 + tx, f32));
    __syncthreads();
    #pragma unroll
    for (int r = ty; r < 32; r += 8) WT[(size_t)(n0 + r) * K + k0 + tx] = t[tx][r];
}

// ---------------- adaLN: mod = silu(c) @ w_adaln + b_adaln; 4-way K-split, wave-coalesced j --------
__global__ __launch_bounds__(256) void adaln_k(const void* __restrict__ c, const void* __restrict__ w,
                                               const void* __restrict__ bv, float* __restrict__ mod,
                                               const int* __restrict__ dflag){
    const bool f32 = (*dflag != 0);
    int b = blockIdx.y;
    int jl = threadIdx.x & 63;                        // j within wave: coalesced 64-wide
    int part = threadIdx.x >> 6;                      // K-quarter per wave
    int j = blockIdx.x * 64 + jl;                     // [0,4608)
    __shared__ float sc[768];
    for (int k = threadIdx.x; k < 768; k += 256){
        float v = loadf(c, b * 768 + k, f32);
        sc[k] = v / (1.f + __expf(-v));
    }
    __syncthreads();
    float acc = 0.f;
    int k0 = part * 192;
    #pragma unroll 4
    for (int k = k0; k < k0 + 192; ++k) acc += sc[k] * loadf(w, (size_t)k * 4608 + j, f32);
    __shared__ float red[4][64];
    red[part][jl] = acc;
    __syncthreads();
    if (part == 0)
        mod[b * 4608 + j] = red[0][jl] + red[1][jl] + red[2][jl] + red[3][jl] + loadf(bv, j, f32);
}

// ---------------- block reduction helper (256 threads) ----------------
__device__ __forceinline__ float2 block_reduce_sum2(float s, float s2){
    #pragma unroll
    for (int m = 32; m >= 1; m >>= 1){
        s  += __shfl_xor(s,  m, 64);
        s2 += __shfl_xor(s2, m, 64);
    }
    __shared__ float red[8];
    int wave = threadIdx.x >> 6;
    if ((threadIdx.x & 63) == 0){ red[wave] = s; red[4 + wave] = s2; }
    __syncthreads();
    return make_float2(red[0] + red[1] + red[2] + red[3],
                       red[4] + red[5] + red[6] + red[7]);
}

// ---------------- LN + modulate + roll(-4,-4) + window partition (chunked) ----------------
__global__ __launch_bounds__(256) void ln_mod_win_k(const void* __restrict__ x, const float* __restrict__ mod,
                                                    bf16* __restrict__ win, int roff,
                                                    const int* __restrict__ dflag){
    const bool f32 = (*dflag != 0);
    int r = roff + blockIdx.x;                        // global window-layout token
    int bw = r >> 6, n = r & 63;
    int b = bw >> 6, widx = bw & 63;
    int hh = (((widx >> 3) << 3) + (n >> 3) + 4) & 63;
    int ww = (((widx & 7) << 3) + (n & 7) + 4) & 63;
    size_t xo = ((size_t)b * 4096 + hh * 64 + ww) * 768;
    int t = threadIdx.x;
    float v0 = loadf(x, xo + t, f32), v1 = loadf(x, xo + t + 256, f32), v2 = loadf(x, xo + t + 512, f32);
    float2 ss = block_reduce_sum2(v0 + v1 + v2, v0 * v0 + v1 * v1 + v2 * v2);
    float mu = ss.x * (1.f / 768.f);
    float rstd = rsqrtf(ss.y * (1.f / 768.f) - mu * mu + 1e-6f);
    const float* mb = mod + b * 4608;                 // [sh_msa | sc_msa | ...]
    bf16* wr = win + (size_t)blockIdx.x * 768;        // chunk-local
    wr[t]       = f2b((v0 - mu) * rstd * (1.f + mb[768 + t])       + mb[t]);
    wr[t + 256] = f2b((v1 - mu) * rstd * (1.f + mb[768 + t + 256]) + mb[t + 256]);
    wr[t + 512] = f2b((v2 - mu) * rstd * (1.f + mb[768 + t + 512]) + mb[t + 512]);
}

// ---------------- LN + modulate (MLP branch; x1 lives in d_out, dtype = output mode) ----------------
__global__ __launch_bounds__(256) void ln_mod2_k(const void* __restrict__ x1, const float* __restrict__ mod,
                                                 bf16* __restrict__ h2, int roff,
                                                 const int* __restrict__ dflag){
    const bool f32 = (*dflag != 0);
    int t0 = roff + blockIdx.x;                       // global image token
    int b = t0 >> 12;
    size_t xo = (size_t)t0 * 768;
    int t = threadIdx.x;
    float v0 = loadf(x1, xo + t, f32), v1 = loadf(x1, xo + t + 256, f32), v2 = loadf(x1, xo + t + 512, f32);
    float2 ss = block_reduce_sum2(v0 + v1 + v2, v0 * v0 + v1 * v1 + v2 * v2);
    float mu = ss.x * (1.f / 768.f);
    float rstd = rsqrtf(ss.y * (1.f / 768.f) - mu * mu + 1e-6f);
    const float* mb = mod + b * 4608;                 // sh_mlp @2304, sc_mlp @3072
    bf16* wr = h2 + (size_t)blockIdx.x * 768;         // chunk-local
    wr[t]       = f2b((v0 - mu) * rstd * (1.f + mb[3072 + t])       + mb[2304 + t]);
    wr[t + 256] = f2b((v1 - mu) * rstd * (1.f + mb[3072 + t + 256]) + mb[2304 + t + 256]);
    wr[t + 512] = f2b((v2 - mu) * rstd * (1.f + mb[3072 + t + 512]) + mb[2304 + t + 512]);
}

// ---------------- windowed attention: MFMA QK^T and PV, one block per (window, head) --------------
// r15: both matmul phases moved to MFMA (6.4 GFLOP total was running on the VALU at ~30 TF).
// Fragment pattern = the verified GEMM mapping (A row=lane&15, k=(lane>>4)*8+i; B col=lane&15;
// C row=lq*4+rr, col=lrow). LDS tiles use the proven 0-conflict GEMM tiling: [k-half][row][32]
// with 16-B chunk c of row r at slot (c+(r>>1))&3. V is staged TRANSPOSED (vt[d][j]) so PV's
// B-fragments are contiguous ds_read_b128. P is written back as bf16 (standard flash-attn
// choice; f32 accumulators everywhere). Softmax (wave-parallel, 4 lanes/row) unchanged.
// Each of the 4 waves computes S rows [w*16, w*16+16): 8 MFMA for QK^T, 8 for PV.
__global__ __launch_bounds__(256) void attn_k(const bf16* __restrict__ qkv, const void* __restrict__ maskm,
                                              const int* __restrict__ rel, const void* __restrict__ rpb,
                                              bf16* __restrict__ ao, int woff,
                                              const int* __restrict__ dflag){
    const bool f32 = (*dflag != 0);
    __shared__ __align__(16) bf16 qs[2 * 64 * 32];    // Q, k-half h, swizzled
    __shared__ __align__(16) bf16 kb[2 * 64 * 32];    // K
    __shared__ __align__(16) bf16 vt[2 * 64 * 32];    // V^T: row=d, k=j
    __shared__ __align__(16) bf16 Pb[2 * 64 * 32];    // softmax(P) in bf16
    __shared__ float Ps[64][68];                      // raw scores for softmax
    int head = blockIdx.x % 12;
    int bw = blockIdx.x / 12;                         // chunk-local window
    int tid = threadIdx.x;
    const bf16* base = qkv + (size_t)bw * 64 * 2304 + head * 64;
    for (int e4 = tid; e4 < 1024; e4 += 256){
        int n = e4 >> 4, d4 = (e4 & 15) * 4;
        size_t o = (size_t)n * 2304 + d4;
        ushort4 qv = *(const ushort4*)(base + o);
        ushort4 kv = *(const ushort4*)(base + o + 768);
        ushort4 vv = *(const ushort4*)(base + o + 1536);
        bf16 q0, q1, q2, q3;
        *(unsigned short*)&q0 = qv.x; *(unsigned short*)&q1 = qv.y;
        *(unsigned short*)&q2 = qv.z; *(unsigned short*)&q3 = qv.w;
        q0 = f2b(b2f(q0) * 0.125f); q1 = f2b(b2f(q1) * 0.125f);   // q * hd^-0.5 (exact in bf16)
        q2 = f2b(b2f(q2) * 0.125f); q3 = f2b(b2f(q3) * 0.125f);
        ushort4 qsc;
        qsc.x = *(unsigned short*)&q0; qsc.y = *(unsigned short*)&q1;
        qsc.z = *(unsigned short*)&q2; qsc.w = *(unsigned short*)&q3;
        int h = d4 >> 5, e = d4 & 31;
        int off = (((e >> 3) + ((n >> 1) & 3)) & 3) * 8 + (e & 7);
        *(ushort4*)&qs[(h * 64 + n) * 32 + off] = qsc;
        *(ushort4*)&kb[(h * 64 + n) * 32 + off] = kv;
        // V^T scatter: element (row=d4+j, k=n)
        int hv = n >> 5, ev_ = n & 31;
        int cv = ev_ >> 3;
        unsigned short vb[4] = {vv.x, vv.y, vv.z, vv.w};
        #pragma unroll
        for (int j = 0; j < 4; ++j){
            int dr = d4 + j;
            int slot = (cv + ((dr >> 1) & 3)) & 3;
            *((unsigned short*)&vt[(hv * 64 + dr) * 32 + slot * 8 + (ev_ & 7)]) = vb[j];
        }
    }
    __syncthreads();
    int lane = tid & 63, w = tid >> 6;
    int lrow = lane & 15, lq = lane >> 4;
    size_t mo = (size_t)((woff + bw) & 63) * 4096;    // window idx within batch
    int arow = w * 16 + lrow;
    int asw = ((lq + ((lrow >> 1) & 3)) & 3) * 8;     // swizzled chunk offset (tile rows mult 16)
    // ---- QK^T: wave w -> S rows [w*16, w*16+16), 2 k-halves x 4 col-tiles ----
    {
        floatx4 sacc[4];
        #pragma unroll
        for (int jt = 0; jt < 4; ++jt) sacc[jt] = floatx4{0.f, 0.f, 0.f, 0.f};
        #pragma unroll
        for (int ksl = 0; ksl < 2; ++ksl){
            short8 aq = *(const short8*)&qs[(ksl * 64 + arow) * 32 + asw];
            #pragma unroll
            for (int jt = 0; jt < 4; ++jt){
                short8 bk = *(const short8*)&kb[(ksl * 64 + jt * 16 + lrow) * 32 + asw];
                sacc[jt] = __builtin_amdgcn_mfma_f32_16x16x32_bf16(aq, bk, sacc[jt], 0, 0, 0);
            }
        }
        #pragma unroll
        for (int jt = 0; jt < 4; ++jt)
            #pragma unroll
            for (int rr = 0; rr < 4; ++rr){
                int i = w * 16 + lq * 4 + rr, j = jt * 16 + lrow;
                Ps[i][j] = sacc[jt][rr]
                         + loadf(rpb, (size_t)rel[i * 64 + j] * 12 + head, f32)
                         + loadf(maskm, mo + i * 64 + j, f32);
            }
    }
    __syncthreads();
    {   // wave-parallel softmax (4 lanes/row); write normalized P as bf16 into swizzled Pb
        int row = tid >> 2, p0 = (tid & 3) * 16;
        float mx = -1e30f;
        #pragma unroll
        for (int j = 0; j < 16; ++j) mx = fmaxf(mx, Ps[row][p0 + j]);
        mx = fmaxf(mx, __shfl_xor(mx, 1, 64));
        mx = fmaxf(mx, __shfl_xor(mx, 2, 64));
        float sum = 0.f;
        float ev[16];
        #pragma unroll
        for (int j = 0; j < 16; ++j){ ev[j] = __expf(Ps[row][p0 + j] - mx); sum += ev[j]; }
        sum += __shfl_xor(sum, 1, 64);
        sum += __shfl_xor(sum, 2, 64);
        float inv = 1.f / sum;
        int h = p0 >> 5, e0 = p0 & 31;
        int rsw = (row >> 1) & 3;
        #pragma unroll
        for (int g = 0; g < 2; ++g){
            int slot = (((e0 >> 3) + g) + rsw) & 3;
            short8 pk;
            #pragma unroll
            for (int j = 0; j < 8; ++j){
                bf16 t = f2b(ev[g * 8 + j] * inv);
                pk[j] = *(short*)&t;
            }
            *(short8*)&Pb[(h * 64 + row) * 32 + slot * 8] = pk;
        }
    }
    __syncthreads();
    // ---- PV: O rows [w*16, w*16+16), B = V^T tiles ----
    {
        floatx4 oacc[4];
        #pragma unroll
        for (int dt = 0; dt < 4; ++dt) oacc[dt] = floatx4{0.f, 0.f, 0.f, 0.f};
        #pragma unroll
        for (int ksl = 0; ksl < 2; ++ksl){
            short8 ap = *(const short8*)&Pb[(ksl * 64 + arow) * 32 + asw];
            #pragma unroll
            for (int dt = 0; dt < 4; ++dt){
                short8 bv2 = *(const short8*)&vt[(ksl * 64 + dt * 16 + lrow) * 32 + asw];
                oacc[dt] = __builtin_amdgcn_mfma_f32_16x16x32_bf16(ap, bv2, oacc[dt], 0, 0, 0);
            }
        }
        #pragma unroll
        for (int dt = 0; dt < 4; ++dt)
            #pragma unroll
            for (int rr = 0; rr < 4; ++rr){
                int i = w * 16 + lq * 4 + rr, d = dt * 16 + lrow;
                ao[((size_t)bw * 64 + i) * 768 + head * 64 + d] = f2b(oacc[dt][rr]);
            }
    }
}

// ---------------- MFMA bf16 GEMM: PERSISTENT grid-stride + continuous 3-buffer pipeline ----------------
// r15 = r11/r13/r14 engine verbatim. Blocks own contiguous mb-fastest tile ranges and run one
// unbroken counted-vmcnt pipeline across tile boundaries; vmcnt hits 0 once per block.
// BN=128 (qkv/fc1): 2x2 waves of 64x64, 48 KB LDS, 3 blk/CU, LPT=4.
// BN=64 (proj/fc2): 4 waves of 32x64, 36 KB LDS, 4 blk/CU, LPT=3.
// Schedule per step (r6-proven): reads(buf T%3) | stage(T+2 -> buf (T+2)%3) | lgkm0+sched_barrier
// | setprio(1) MFMA setprio(0) | vmcnt(LPT) | s_barrier.  WAR ledger: a buffer's readers
// lgkm-drain before their step's exit barrier; the buffer is restaged >= 2 barriers later.
// LDS layout: [rows][32] (64 B/row); chunk c of row r at slot (c+(r>>1))&3 -> ds_read_b128
// 2-way bank-aliased (free; 0 conflicts measured r0-r14).
// EPI: 0 store bf16; 1 exact GELU bf16; 2 proj epilogue (unwindow+roll+residual+gate -> x1);
//      3 fc2 epilogue (out = x1 + g_mlp * v).
template<int EPI, int BN>
__global__ __launch_bounds__(256, (BN == 128) ? 3 : 4)
void gemm_k(const bf16* __restrict__ A, const bf16* __restrict__ BT,
            const void* __restrict__ bias, void* __restrict__ Cout,
            int N, int K, int roff,
            const void* __restrict__ xres, const float* __restrict__ mod,
            const void* __restrict__ x1,
            const int* __restrict__ dflag, int nMB, int total){
    constexpr int MFR = (BN == 128) ? 4 : 2;          // A-frags per wave
    constexpr int LPT = (BN == 128) ? 4 : 3;          // gloads per wave per step
    const bool f32 = (*dflag != 0);
    __shared__ __align__(16) bf16 As[3][128 * 32];
    __shared__ __align__(16) bf16 Bs[3][BN * 32];

    int tid = threadIdx.x;
    int wave = tid >> 6, lane = tid & 63;
    int wm = (BN == 128) ? (wave >> 1) * 64 : wave * 32;
    int wn = (BN == 128) ? (wave & 1) * 64 : 0;
    int lrow = lane & 15, lq = lane >> 4;

    // persistent work range: tiles [first, first+myLen), linear idx = nb*nMB + mb (mb fastest)
    int G = (int)gridDim.x, bid = (int)blockIdx.x;
    int q = total / G, r = total % G;
    int myLen = q + (bid < r ? 1 : 0);
    int first = bid * q + (bid < r ? bid : r);
    const int nkt = K >> 5;                           // 24 or 96
    int TS = myLen * nkt;

    // staging lane geometry (chunk c = ((lane&3)-((lane>>3)&3))&3; base rows mult of 16)
    int sc8 = ((((lane & 3) - ((lane >> 3) & 3)) & 3)) * 8;
    int srw = lane >> 2;
    int lofsA0 = (wave * 32) * 32;
    int lofsA1 = (wave * 32 + 16) * 32;
    int lofsB  = (BN == 128) ? lofsA0 : (wave * 16) * 32;
    int wB     = (BN == 128) ? wave * 32 : wave * 16;

    // fragment read offsets (inverse swizzle; (row>>1)&3 == (lrow>>1)&3)
    int fsw = ((lq + ((lrow >> 1) & 3)) & 3) * 8;
    int aoff = (wm + lrow) * 32 + fsw;
    int boff = (wn + lrow) * 32 + fsw;

    floatx4 acc[MFR][4];
    #pragma unroll
    for (int i = 0; i < MFR; ++i)
        #pragma unroll
        for (int j = 0; j < 4; ++j) acc[i][j] = floatx4{0.f, 0.f, 0.f, 0.f};

    // stage-side state
    int sIdx = first, sT = 0;
    const bf16 *gA, *gB;
    auto setPtrs = [&](){
        int m0s = (sIdx % nMB) * 128;
        int n0s = (sIdx / nMB) * BN;
        gA = A  + (size_t)(m0s + wave * 32 + srw) * K + sc8;
        gB = BT + (size_t)(n0s + wB + srw) * K + sc8;
    };
    setPtrs();
    auto stageStep = [&](int buf){
        size_t kof = (size_t)sT * 32;
        gload16(gA + kof,                  As[buf] + lofsA0);
        gload16(gA + kof + (size_t)16 * K, As[buf] + lofsA1);
        gload16(gB + kof,                  Bs[buf] + lofsB);
        if constexpr (BN == 128)
            gload16(gB + kof + (size_t)16 * K, Bs[buf] + lofsA1);
        if (++sT == nkt){ sT = 0; ++sIdx; setPtrs(); }
    };

    stageStep(0); stageStep(1);
    vmwait<LPT>();                                    // step 0 landed; step 1 in flight
    bar();

    // reader-side state
    int rIdx = first, rT = 0;
    int rm0 = (rIdx % nMB) * 128, rn0 = (rIdx / nMB) * BN;
    float bb[4];
    int bN0 = -1;
    int cur = 0, nx2 = 2;

    for (int T = 0; T < TS; ++T){
        short8 af[MFR], bfr[4];
        #pragma unroll
        for (int f = 0; f < MFR; ++f) af[f]  = *(const short8*)(As[cur] + aoff + f * 512);
        #pragma unroll
        for (int f = 0; f < 4;   ++f) bfr[f] = *(const short8*)(Bs[cur] + boff + f * 512);
        bool more = (T + 2 < TS);
        if (more) stageStep(nx2);                     // buf nx2's readers drained 2 bars ago
        lgkm0_fence();                                // frags in regs; MFMAs pinned below
        __builtin_amdgcn_s_setprio(1);
        #pragma unroll
        for (int mf = 0; mf < MFR; ++mf)
            #pragma unroll
            for (int nf = 0; nf < 4; ++nf)
                acc[mf][nf] = __builtin_amdgcn_mfma_f32_16x16x32_bf16(af[mf], bfr[nf], acc[mf][nf], 0, 0, 0);
        __builtin_amdgcn_s_setprio(0);
        if (T + 1 < TS){
            if (more) vmwait<LPT>();                  // T+1 landed; T+2 in flight
            else      vmwait<0>();                    // block tail: drain
            bar();
        }
        cur = (cur == 2) ? 0 : cur + 1;
        nx2 = (nx2 == 2) ? 0 : nx2 + 1;
        if (++rT == nkt){                             // tile rIdx complete -> epilogue
            rT = 0;
            if (rn0 != bN0){                          // hoist bias for this nb (rare reload)
                bN0 = rn0;
                #pragma unroll
                for (int nf = 0; nf < 4; ++nf) bb[nf] = loadf(bias, rn0 + wn + nf * 16 + lrow, f32);
            }
            #pragma unroll
            for (int mf = 0; mf < MFR; ++mf){
                #pragma unroll
                for (int nf = 0; nf < 4; ++nf){
                    #pragma unroll
                    for (int rr = 0; rr < 4; ++rr){
                        int grow = rm0 + wm + mf * 16 + lq * 4 + rr;   // chunk-local row
                        int gcol = rn0 + wn + nf * 16 + lrow;
                        float v = acc[mf][nf][rr] + bb[nf];
                        if (EPI == 0){
                            ((bf16*)Cout)[(size_t)grow * N + gcol] = f2b(v);
                        } else if (EPI == 1){
                            float g = 0.5f * v * (1.f + erff(v * 0.70710678118654752f));
                            ((bf16*)Cout)[(size_t)grow * N + gcol] = f2b(g);
                        } else if (EPI == 2){
                            int gr = roff + grow;                    // global window-layout row
                            int bw = gr >> 6, n = gr & 63;
                            int b = bw >> 6, widx = bw & 63;
                            int hh = (((widx >> 3) << 3) + (n >> 3) + 4) & 63;
                            int ww = (((widx & 7) << 3) + (n & 7) + 4) & 63;
                            size_t t = ((size_t)b * 4096 + hh * 64 + ww) * 768 + gcol;
                            float gm = mod[b * 4608 + 1536 + gcol];   // g_msa
                            float res = loadf(xres, t, f32) + gm * v;
                            if (f32) ((float*)Cout)[t] = res; else ((bf16*)Cout)[t] = f2b(res);
                        } else {
                            int gr = roff + grow;                    // global image row
                            int b = gr >> 12;
                            float gm = mod[b * 4608 + 3840 + gcol];   // g_mlp
                            size_t t = (size_t)gr * N + gcol;
                            float res = loadf(x1, t, f32) + gm * v;   // read x1 then overwrite
                            if (f32) ((float*)Cout)[t] = res; else ((bf16*)Cout)[t] = f2b(res);
                        }
                    }
                }
            }
            #pragma unroll
            for (int i = 0; i < MFR; ++i)
                #pragma unroll
                for (int j = 0; j < 4; ++j) acc[i][j] = floatx4{0.f, 0.f, 0.f, 0.f};
            ++rIdx;
            rm0 = (rIdx % nMB) * 128; rn0 = (rIdx / nMB) * BN;
        }
    }
}

extern "C" void kernel_launch(void* const* d_in, const int* in_sizes, int n_in,
                              void* d_out, int out_size, void* d_ws, size_t ws_size,
                              hipStream_t stream){
    const void* x       = d_in[0];
    const void* c       = d_in[1];
    const void* maskm   = d_in[2];
    const int*  rel     = (const int*)d_in[3];
    const void* w_adaln = d_in[4];
    const void* b_adaln = d_in[5];
    const void* w_qkv   = d_in[6];
    const void* b_qkv   = d_in[7];
    const void* rpb     = d_in[8];
    const void* w_proj  = d_in[9];
    const void* b_proj  = d_in[10];
    const void* w_fc1   = d_in[11];
    const void* b_fc1   = d_in[12];
    const void* w_fc2   = d_in[13];
    const void* b_fc2   = d_in[14];

    // MSA chunk: capped at 8192 (win 12.5 + qkv 37.7 + ao 12.5 MB all L3-resident; r10 lesson)
    int Mc = 4096;
    for (int cand = 8192; cand >= 256; cand >>= 1){
        if (FIXED_WS + (size_t)cand * 7680u <= ws_size){ Mc = cand; break; }
    }
    // MLP chunk: 16384 if it fits (fc1 gets 96-step persistent pipelines; proven r13 win).
    // fc2 runs in 8192-row SUB-chunks inside it (r13 lesson: fc2's A-half must be L3-hot).
    int Mc2 = Mc;
    if (FIXED_WS + 16384ull * 7680u <= ws_size && Mc == 8192) Mc2 = 16384;
    const int nc   = 32768 / Mc;
    const int nc2  = 32768 / Mc2;
    const int nMB  = Mc  / 128;
    const int nMB2 = Mc2 / 128;
    const int McF  = (Mc2 > 8192) ? 8192 : Mc2;        // fc2 sub-chunk rows
    const int nMBF = McF / 128;

    char* ws = (char*)d_ws;
    int*  dflag  = (int*)(ws);
    float* mod   = (float*)(ws + 256);
    bf16* wqkvT  = (bf16*)(ws + 147712);
    bf16* wprojT = (bf16*)(ws + 3686656);
    bf16* wfc1T  = (bf16*)(ws + 4866304);
    bf16* wfc2T  = (bf16*)(ws + 9584896);
    bf16* win_c  = (bf16*)(ws + FIXED_WS);                          // Mc*768 bf16
    bf16* big_c  = (bf16*)(ws + FIXED_WS + (size_t)Mc * 1536);      // qkv (MSA layout)
    bf16* ao_c   = (bf16*)(ws + FIXED_WS + (size_t)Mc * 6144);      // Mc*768 bf16 (MSA only)
    bf16* h2_c   = (bf16*)(ws + FIXED_WS);                          // Mc2*768 bf16 (MLP layout)
    bf16* fc1o_c = (bf16*)(ws + FIXED_WS + (size_t)Mc2 * 1536);     // Mc2*3072 bf16
    void* x1     = d_out;                                           // aliased into d_out
    void* out    = d_out;

    detect_k<<<1, 256, 0, stream>>>(x, dflag);

    dim3 tb(32, 8);
    transpose_k<<<dim3(2304/32, 768/32),  tb, 0, stream>>>(w_qkv,  wqkvT,  768, 2304, dflag);
    transpose_k<<<dim3(768/32,  768/32),  tb, 0, stream>>>(w_proj, wprojT, 768, 768, dflag);
    transpose_k<<<dim3(3072/32, 768/32),  tb, 0, stream>>>(w_fc1,  wfc1T,  768, 3072, dflag);
    transpose_k<<<dim3(768/32,  3072/32), tb, 0, stream>>>(w_fc2,  wfc2T,  3072, 768, dflag);
    adaln_k<<<dim3(72, 8), 256, 0, stream>>>(c, w_adaln, b_adaln, mod, dflag);

    const int G128 = 768;                              // 3 blk/CU x 256 CU
    const int G64  = 1024;                             // 4 blk/CU x 256 CU
    // ---- MSA phase, chunked over windows ----
    for (int ch = 0; ch < nc; ++ch){
        int roff = ch * Mc;
        ln_mod_win_k<<<Mc, 256, 0, stream>>>(x, mod, win_c, roff, dflag);
        int tqkv = nMB * 18;
        gemm_k<0,128><<<(tqkv < G128 ? tqkv : G128), 256, 0, stream>>>(win_c, wqkvT, b_qkv, big_c,
                                                    2304, 768, 0, nullptr, nullptr, nullptr, dflag, nMB, tqkv);
        attn_k<<<(Mc/64) * 12, 256, 0, stream>>>(big_c, maskm, rel, rpb, ao_c, roff / 64, dflag);
        int tproj = nMB * 12;
        gemm_k<2,64><<<(tproj < G64 ? tproj : G64), 256, 0, stream>>>(ao_c, wprojT, b_proj, x1,
                                                   768, 768, roff, x, mod, nullptr, dflag, nMB, tproj);
    }
    // ---- MLP phase: big chunk for ln+fc1 (long pipelines), fc2 in L3-hot sub-chunks ----
    for (int ch = 0; ch < nc2; ++ch){
        int roff = ch * Mc2;
        ln_mod2_k<<<Mc2, 256, 0, stream>>>(x1, mod, h2_c, roff, dflag);
        int tfc1 = nMB2 * 24;
        gemm_k<1,128><<<(tfc1 < G128 ? tfc1 : G128), 256, 0, stream>>>(h2_c, wfc1T, b_fc1, fc1o_c,
                                                    3072, 768, 0, nullptr, nullptr, nullptr, dflag, nMB2, tfc1);
        for (int sub = 0; sub < Mc2 / McF; ++sub){
            int tfc2 = nMBF * 12;
            gemm_k<3,64><<<(tfc2 < G64 ? tfc2 : G64), 256, 0, stream>>>(
                fc1o_c + (size_t)sub * McF * 3072, wfc2T, b_fc2, out,
                768, 3072, roff + sub * McF, nullptr, mod, x1, dflag, nMBF, tfc2);
        }
    }
}